// Round 15
// baseline (481.545 us; speedup 1.0000x reference)
//
#include <hip/hip_runtime.h>
#include <cstdint>
#include <cstddef>

// Problem constants: B=16, E=16, T=1024, F=80, H=8, 3H=24 qkv channels
#define NB 16
#define NT 1024
#define NF 80
#define NH 8
#define FP 96   // qkv f padded to 96 (3 x K=32 MFMA steps); pad is zero
#define FS 84   // channels-last padded f-sites (site s <-> f = s-1; 0,81..83 zero)
#define SP 1032 // time_attn P-strip row stride (fp16)
#define KP 108  // time_attn kst/q_lds K-row stride (fp16)
#define VP 264  // time_attn V^T-chunk row stride (fp16): 80 rows x 256 t

typedef _Float16 v8h __attribute__((ext_vector_type(8)));  // 8 fp16 (4 VGPRs)
typedef _Float16 v4h __attribute__((ext_vector_type(4)));  // 4 fp16 (8 B)
typedef _Float16 v2h __attribute__((ext_vector_type(2)));  // 2 fp16 (4 B)
typedef float v4f __attribute__((ext_vector_type(4)));     // mfma f32x4 acc

static const size_t OUT_ELEMS = (size_t)NB * 16 * NT * NF;  // 20,971,520

// ---------------------------------------------------------------------------
// conv3x3 SAME as MFMA implicit GEMM, reading fp32 NCHW input DIRECTLY
// (channels-last transpose fused into the axt staging). Emits per-block
// per-channel partial (sum, sumsq) for downstream BN.
// ---------------------------------------------------------------------------
template <int OCT, int OSTRIDE, bool QSCALE, bool PADOUT>
__global__ __launch_bounds__(512) void conv_mfma_k(
    const float* __restrict__ src, const float* __restrict__ w,
    const float* __restrict__ bias, _Float16* __restrict__ out,
    float* __restrict__ pstats, int CO) {
  __shared__ _Float16 axt[18][FS * 16];            // 48.4 KB
  __shared__ _Float16 wlds[3][2][OCT * 16][32];
  __shared__ float blds[32];
  __shared__ float wsum[8][OCT][16], wsq[8][OCT][16];
  const int b = blockIdx.y, t0 = blockIdx.x * 16;
  const int tid = threadIdx.x;
  const int NW = 3 * 2 * OCT * 16 * 32;
  for (int i = tid; i < NW; i += 512) {
    int kk = i % 32;
    int oc = (i / 32) % (OCT * 16);
    int ck = (i / (32 * OCT * 16)) % 2;
    int kt = i / (64 * OCT * 16);
    int kg = ck * 32 + kk;
    float v = 0.f;
    if (oc < CO && kg < 48) {
      int c = kg & 15, kf = kg >> 4;
      v = w[((oc * 16 + c) * 3 + kt) * 3 + kf];
      if (QSCALE && oc < 8) v *= 0.25f;
    }
    wlds[kt][ck][oc][kk] = (_Float16)v;
  }
  if (tid < 32) {
    float v = (tid < CO) ? bias[tid] : 0.f;
    if (QSCALE && tid < 8) v *= 0.25f;
    blds[tid] = v;
  }
  // ---- zero pad sites 0, 81..83 ----
  for (int i = tid; i < 144; i += 512) {
    int r = i / 8, j = i % 8;
    int sidx = j >> 1, half = j & 1;
    int site = (sidx == 0) ? 0 : 80 + sidx;
    *(v8h*)&axt[r][site * 16 + half * 8] = (v8h)(_Float16)0.f;
  }
  // ---- stage 18 rows channels-last from fp32 NCHW (cl_k fused) ----
  for (int i = tid; i < 18 * 80; i += 512) {
    int r = i / 80, f = i % 80;
    int t = t0 + r - 1;
    v8h lo = (v8h)(_Float16)0.f, hi = (v8h)(_Float16)0.f;
    if (t >= 0 && t < NT) {
#pragma unroll
      for (int c = 0; c < 8; ++c)
        lo[c] = (_Float16)src[((size_t)(b * 16 + c) * NT + t) * NF + f];
#pragma unroll
      for (int c = 0; c < 8; ++c)
        hi[c] = (_Float16)src[((size_t)(b * 16 + 8 + c) * NT + t) * NF + f];
    }
    *(v8h*)&axt[r][(f + 1) * 16] = lo;
    *(v8h*)&axt[r][(f + 1) * 16 + 8] = hi;
  }
  __syncthreads();
  const int wv = tid >> 6, l = tid & 63, lg = l >> 4, lm = l & 15;
  v8h bfr[3][2][OCT];
#pragma unroll
  for (int kt = 0; kt < 3; ++kt)
#pragma unroll
    for (int ck = 0; ck < 2; ++ck)
#pragma unroll
      for (int ot = 0; ot < OCT; ++ot)
        bfr[kt][ck][ot] = *(const v8h*)&wlds[kt][ck][ot * 16 + lm][lg * 8];
  float s1[OCT], s2[OCT];
#pragma unroll
  for (int ot = 0; ot < OCT; ++ot) { s1[ot] = 0.f; s2[ot] = 0.f; }
#pragma unroll
  for (int li = 0; li < 2; ++li) {
    const int lt = wv * 2 + li;
    const int tt = t0 + lt;
#pragma unroll
    for (int f0 = 0; f0 < 80; f0 += 16) {
      v4f acc[OCT];
#pragma unroll
      for (int ot = 0; ot < OCT; ++ot) acc[ot] = (v4f){0.f, 0.f, 0.f, 0.f};
#pragma unroll
      for (int kt = 0; kt < 3; ++kt)
#pragma unroll
        for (int ck = 0; ck < 2; ++ck) {
          v8h afr =
              *(const v8h*)&axt[lt + kt][(f0 + lm) * 16 + ck * 32 + lg * 8];
#pragma unroll
          for (int ot = 0; ot < OCT; ++ot)
            acc[ot] = __builtin_amdgcn_mfma_f32_16x16x32_f16(
                afr, bfr[kt][ck][ot], acc[ot], 0, 0, 0);
        }
#pragma unroll
      for (int ot = 0; ot < OCT; ++ot) {
        int oc = ot * 16 + lm;
        if (oc < CO) {
          float bv = blds[oc];
          v4h o;
#pragma unroll
          for (int r = 0; r < 4; ++r) {
            float v = acc[ot][r] + bv;
            s1[ot] += v;
            s2[ot] += v * v;
            o[r] = (_Float16)v;
          }
          *(v4h*)(out + ((size_t)(b * CO + oc) * NT + tt) * OSTRIDE + f0 +
                  lg * 4) = o;
        }
      }
    }
  }
  if constexpr (PADOUT) {
    for (int i = tid; i < CO * 16 * 2; i += 512) {
      int oc = i / 32, lt2 = (i / 2) % 16, half = i & 1;
      int4 z = {0, 0, 0, 0};
      ((int4*)(out + ((size_t)(b * CO + oc) * NT + t0 + lt2) * OSTRIDE +
               80))[half] = z;
    }
  }
#pragma unroll
  for (int ot = 0; ot < OCT; ++ot) {
    float a = s1[ot], b2 = s2[ot];
    a += __shfl_xor(a, 16);
    a += __shfl_xor(a, 32);
    b2 += __shfl_xor(b2, 16);
    b2 += __shfl_xor(b2, 32);
    if (l < 16) { wsum[wv][ot][lm] = a; wsq[wv][ot][lm] = b2; }
  }
  __syncthreads();
  if (tid < CO) {
    int ot = tid >> 4, lmm = tid & 15;
    float a = 0.f, b2 = 0.f;
#pragma unroll
    for (int w2 = 0; w2 < 8; ++w2) { a += wsum[w2][ot][lmm]; b2 += wsq[w2][ot][lmm]; }
    int bid = blockIdx.y * 64 + blockIdx.x;  // grid (64,16) -> 1024 blocks
    pstats[tid * 1024 + bid] = a;
    pstats[(CO + tid) * 1024 + bid] = b2;
  }
}

// ---------------------------------------------------------------------------
// BN finalize from conv partials: grid = C blocks x 256 threads.
// ---------------------------------------------------------------------------
__global__ __launch_bounds__(256) void bn_finalize2_k(
    const float* __restrict__ pstats, float* __restrict__ stats, int C) {
  const int c = blockIdx.x;
  float a = 0.f, b2 = 0.f;
  for (int i = threadIdx.x; i < 1024; i += 256) {
    a += pstats[c * 1024 + i];
    b2 += pstats[(C + c) * 1024 + i];
  }
  __shared__ float rs[256], rs2[256];
  rs[threadIdx.x] = a;
  rs2[threadIdx.x] = b2;
  __syncthreads();
  for (int off = 128; off > 0; off >>= 1) {
    if ((int)threadIdx.x < off) {
      rs[threadIdx.x] += rs[threadIdx.x + off];
      rs2[threadIdx.x] += rs2[threadIdx.x + off];
    }
    __syncthreads();
  }
  if (threadIdx.x == 0) {
    const float N = 16.0f * (float)(NT * NF);
    float mean = rs[0] / N;
    float var = rs2[0] / N - mean * mean;
    stats[c * 2 + 0] = mean;
    stats[c * 2 + 1] = rsqrtf(var + 1e-5f);
  }
}

// BN affine + relu in place on fp16 qkv -- q,k channels only (v handled by
// vtrans_bn_k).
__global__ __launch_bounds__(256) void bn_apply_qk_k(
    _Float16* __restrict__ qkv, const float* __restrict__ stats,
    const float* __restrict__ gq, const float* __restrict__ bq,
    const float* __restrict__ gk, const float* __restrict__ bk) {
  const size_t n8 = (size_t)NB * 16 * NT * 12;
  const size_t stride = (size_t)gridDim.x * blockDim.x;
  for (size_t idx = (size_t)blockIdx.x * blockDim.x + threadIdx.x; idx < n8;
       idx += stride) {
    int fc = (int)(idx % 12);
    if (fc >= 10) continue;  // f 80..95 stays zero
    int ch = (int)((idx / (NT * 12)) % 16);
    int b = (int)(idx / (16 * NT * 12));
    size_t rest = idx % (NT * 12);
    size_t v8idx = ((size_t)(b * 24 + ch) * NT * 12) + rest;
    float g, be;
    if (ch < 8) { g = gq[ch]; be = bq[ch]; }
    else { g = gk[ch - 8]; be = bk[ch - 8]; }
    float mean = stats[ch * 2 + 0], invstd = stats[ch * 2 + 1];
    v8h v = ((v8h*)qkv)[v8idx];
#pragma unroll
    for (int j = 0; j < 8; ++j) {
      float f = (float)v[j];
      f = fmaxf((f - mean) * invstd * g + be, 0.f);
      v[j] = (_Float16)f;
    }
    ((v8h*)qkv)[v8idx] = v;
  }
}

// ---------------------------------------------------------------------------
// V: BN+relu (write back normalized v to qkv) + transpose -> vT [bh][80][1024]
// ---------------------------------------------------------------------------
__global__ __launch_bounds__(256) void vtrans_bn_k(
    _Float16* __restrict__ qkv, const float* __restrict__ stats,
    const float* __restrict__ gv, const float* __restrict__ bv,
    _Float16* __restrict__ vT) {
  __shared__ _Float16 tile[128 * 100];  // 25.6 KB
  const int tc = blockIdx.x, bh = blockIdx.y;
  const int b = bh >> 3, h = bh & 7;
  const int t0 = tc * 128;
  _Float16* src = qkv + ((size_t)(b * 24 + 16 + h) * NT + t0) * FP;
  const int tid = threadIdx.x;
  const float mean = stats[(16 + h) * 2 + 0];
  const float invstd = stats[(16 + h) * 2 + 1];
  const float g = gv[h], be = bv[h];
  for (int i = tid; i < 1536; i += 256) {
    int row = i / 12, c = i % 12;
    v8h v = *(v8h*)(src + (size_t)row * FP + c * 8);
    if (c < 10) {  // f 80..95 stays zero
#pragma unroll
      for (int j = 0; j < 8; ++j) {
        float f = (float)v[j];
        f = fmaxf((f - mean) * invstd * g + be, 0.f);
        v[j] = (_Float16)f;
      }
      *(v8h*)(src + (size_t)row * FP + c * 8) = v;  // normalized v back
    }
    int2* d = (int2*)&tile[row * 100 + c * 8];
    int4 vi = __builtin_bit_cast(int4, v);
    d[0] = make_int2(vi.x, vi.y);
    d[1] = make_int2(vi.z, vi.w);
  }
  __syncthreads();
  _Float16* dst = vT + (size_t)bh * 80 * NT + t0;
  for (int i = tid; i < 1280; i += 256) {
    int f = i / 16, c8 = i % 16;
    v8h v;
#pragma unroll
    for (int j = 0; j < 8; ++j) v[j] = tile[(c8 * 8 + j) * 100 + f];
    *(v8h*)(dst + (size_t)f * NT + c8 * 8) = v;
  }
}

// ---------------------------------------------------------------------------
// Time attention, MFMA fp16. Block = (32-query strip, b), 512 threads.
// R8's in-register-softmax design (correctness-proven) with
// __launch_bounds__(512,1): LDS caps us at 1 block/CU anyway, so grant the
// full 256-VGPR budget -> ~200 live regs, spill-free. QK accumulators stay
// in registers; cross-wave softmax via wred; single normalized-P write; PV
// B-fragments contiguous from V^T chunks.
// ---------------------------------------------------------------------------
__global__ __launch_bounds__(512, 1) void time_attn_k(
    const _Float16* __restrict__ qkv, const _Float16* __restrict__ vT,
    float* __restrict__ attn_out, float* __restrict__ aw_avg) {
  __shared__ _Float16 s_lds[32 * SP];   // 64.5 KB: normalized P strip / ored
  __shared__ _Float16 q_lds[32 * KP];   // 6.9 KB
  __shared__ _Float16 kst[256 * KP];    // 55.3 KB: K chunks / V^T chunks union
  __shared__ float wred[2][8][32];      // 2 KB cross-wave reduce
  const int b = blockIdx.y, t0 = blockIdx.x * 32;
  const int tid = threadIdx.x;
  const int w = tid >> 6, l = tid & 63, lg = l >> 4, lm = l & 15;

  float avg[4][2][2][4];  // [s][tt][qt][r]
#pragma unroll
  for (int s4 = 0; s4 < 4; ++s4)
#pragma unroll
    for (int tt = 0; tt < 2; ++tt)
#pragma unroll
      for (int qt = 0; qt < 2; ++qt)
#pragma unroll
        for (int r = 0; r < 4; ++r) avg[s4][tt][qt][r] = 0.f;

  int4 rb[6];
  auto gloadK = [&](const _Float16* kb, int chunk) {
    const int4* src = (const int4*)(kb + (size_t)chunk * 256 * FP);
#pragma unroll
    for (int u = 0; u < 6; ++u) rb[u] = src[tid + u * 512];
  };
  auto lwriteK = [&]() {
#pragma unroll
    for (int u = 0; u < 6; ++u) {
      int i = tid + u * 512, row = i / 12, j = i % 12;
      int2* d = (int2*)&kst[row * KP + j * 8];
      d[0] = make_int2(rb[u].x, rb[u].y);
      d[1] = make_int2(rb[u].z, rb[u].w);
    }
  };
  auto gloadV = [&](const int4* vt4, int chunk) {
#pragma unroll
    for (int u = 0; u < 5; ++u) {
      int i = tid + u * 512, row = i >> 5, c = i & 31;
      rb[u] = vt4[row * 128 + chunk * 32 + c];
    }
  };
  auto lwriteV = [&]() {
#pragma unroll
    for (int u = 0; u < 5; ++u) {
      int i = tid + u * 512, row = i >> 5, c = i & 31;
      *(int4*)&kst[row * VP + c * 8] = rb[u];
    }
  };
  auto qstage = [&](const _Float16* qb) {
    if (tid < 384) {
      int4 qreg = ((const int4*)qb)[tid];
      int row = tid / 12, j = tid % 12;
      int2* d = (int2*)&q_lds[row * KP + j * 8];
      d[0] = make_int2(qreg.x, qreg.y);
      d[1] = make_int2(qreg.z, qreg.w);
    }
  };

  // ---- preamble: K0, Q(h=0) staged; K1 in regs ----
  {
    const _Float16* kb0 = qkv + (size_t)(b * 24 + 8) * NT * FP;
    gloadK(kb0, 0);
    lwriteK();
    qstage(qkv + ((size_t)(b * 24 + 0) * NT + t0) * FP);
    gloadK(kb0, 1);
  }
  __syncthreads();

  for (int h = 0; h < NH; ++h) {
    const _Float16* kb = qkv + (size_t)(b * 24 + 8 + h) * NT * FP;
    const int4* vt4 = (const int4*)(vT + (size_t)(b * 8 + h) * 80 * NT);
    const _Float16* kbn = qkv + (size_t)(b * 24 + 8 + h + 1) * NT * FP;
    // A fragments (Q)
    v8h afr[2][3];
#pragma unroll
    for (int qt = 0; qt < 2; ++qt)
#pragma unroll
      for (int kk = 0; kk < 3; ++kk) {
        v4h a0 = *(const v4h*)&q_lds[(qt * 16 + lm) * KP + kk * 32 + lg * 8];
        v4h a1 =
            *(const v4h*)&q_lds[(qt * 16 + lm) * KP + kk * 32 + lg * 8 + 4];
        afr[qt][kk] = __builtin_shufflevector(a0, a1, 0, 1, 2, 3, 4, 5, 6, 7);
      }
    // ---- QK phase: chunks K0..K3 -> sReg ----
    v4f sReg[4][2][2];
#pragma unroll
    for (int s = 0; s < 4; ++s) {
#pragma unroll
      for (int tt = 0; tt < 2; ++tt) {
        const int rbase = ((w * 2 + tt) * 16 + lm) * KP;
        v8h bfr[3];
#pragma unroll
        for (int kk = 0; kk < 3; ++kk) {
          v4h b0 = *(const v4h*)&kst[rbase + kk * 32 + lg * 8];
          v4h b1 = *(const v4h*)&kst[rbase + kk * 32 + lg * 8 + 4];
          bfr[kk] = __builtin_shufflevector(b0, b1, 0, 1, 2, 3, 4, 5, 6, 7);
        }
#pragma unroll
        for (int qt = 0; qt < 2; ++qt) {
          v4f acc = (v4f){0.f, 0.f, 0.f, 0.f};
#pragma unroll
          for (int kk = 0; kk < 3; ++kk)
            acc = __builtin_amdgcn_mfma_f32_16x16x32_f16(afr[qt][kk], bfr[kk],
                                                         acc, 0, 0, 0);
          sReg[s][tt][qt] = acc;
        }
      }
      __syncthreads();  // K chunk consumers done
      if (s < 2) {
        lwriteK();
        gloadK(kb, s + 2);
        __syncthreads();
      } else if (s == 2) {
        lwriteK();  // K3
        gloadV(vt4, 0);
        __syncthreads();
      } else {
        lwriteV();  // V0 (visibility via softmax barriers)
        gloadV(vt4, 1);
      }
    }
    // ---- softmax (in-register, cross-wave via wred) ----
    {
      float pm[2][4];
#pragma unroll
      for (int qt = 0; qt < 2; ++qt)
#pragma unroll
        for (int r = 0; r < 4; ++r) {
          float m = -1e30f;
#pragma unroll
          for (int s4 = 0; s4 < 4; ++s4)
#pragma unroll
            for (int tt = 0; tt < 2; ++tt)
              m = fmaxf(m, sReg[s4][tt][qt][r]);
          pm[qt][r] = m;
        }
#pragma unroll
      for (int mk = 8; mk; mk >>= 1)
#pragma unroll
        for (int qt = 0; qt < 2; ++qt)
#pragma unroll
          for (int r = 0; r < 4; ++r)
            pm[qt][r] = fmaxf(pm[qt][r], __shfl_xor(pm[qt][r], mk, 16));
      if (lm == 0) {
#pragma unroll
        for (int qt = 0; qt < 2; ++qt)
#pragma unroll
          for (int r = 0; r < 4; ++r)
            wred[0][w][qt * 16 + lg * 4 + r] = pm[qt][r];
      }
      __syncthreads();
      float mg[2][4];
#pragma unroll
      for (int qt = 0; qt < 2; ++qt)
#pragma unroll
        for (int r = 0; r < 4; ++r) {
          float m = -1e30f;
#pragma unroll
          for (int ww = 0; ww < 8; ++ww)
            m = fmaxf(m, wred[0][ww][qt * 16 + lg * 4 + r]);
          mg[qt][r] = m;
        }
      float ps[2][4];
#pragma unroll
      for (int qt = 0; qt < 2; ++qt)
#pragma unroll
        for (int r = 0; r < 4; ++r) ps[qt][r] = 0.f;
#pragma unroll
      for (int s4 = 0; s4 < 4; ++s4)
#pragma unroll
        for (int tt = 0; tt < 2; ++tt)
#pragma unroll
          for (int qt = 0; qt < 2; ++qt)
#pragma unroll
            for (int r = 0; r < 4; ++r) {
              float e = __expf(sReg[s4][tt][qt][r] - mg[qt][r]);
              sReg[s4][tt][qt][r] = e;
              ps[qt][r] += e;
            }
#pragma unroll
      for (int mk = 8; mk; mk >>= 1)
#pragma unroll
        for (int qt = 0; qt < 2; ++qt)
#pragma unroll
          for (int r = 0; r < 4; ++r)
            ps[qt][r] += __shfl_xor(ps[qt][r], mk, 16);
      if (lm == 0) {
#pragma unroll
        for (int qt = 0; qt < 2; ++qt)
#pragma unroll
          for (int r = 0; r < 4; ++r)
            wred[1][w][qt * 16 + lg * 4 + r] = ps[qt][r];
      }
      __syncthreads();
      float inv[2][4];
#pragma unroll
      for (int qt = 0; qt < 2; ++qt)
#pragma unroll
        for (int r = 0; r < 4; ++r) {
          float ssum = 0.f;
#pragma unroll
          for (int ww = 0; ww < 8; ++ww)
            ssum += wred[1][ww][qt * 16 + lg * 4 + r];
          inv[qt][r] = 1.f / ssum;
        }
#pragma unroll
      for (int s4 = 0; s4 < 4; ++s4)
#pragma unroll
        for (int tt = 0; tt < 2; ++tt)
#pragma unroll
          for (int qt = 0; qt < 2; ++qt)
#pragma unroll
            for (int r = 0; r < 4; ++r) {
              float p = sReg[s4][tt][qt][r] * inv[qt][r];
              avg[s4][tt][qt][r] += p;
              s_lds[(qt * 16 + lg * 4 + r) * SP + s4 * 256 +
                    (w * 2 + tt) * 16 + lm] = (_Float16)p;
            }
      __syncthreads();  // P + V0 staging visible
    }
    // ---- PV phase: chunks V0..V3 ----
    v4f accO[2][5];
#pragma unroll
    for (int qt = 0; qt < 2; ++qt)
#pragma unroll
      for (int ft = 0; ft < 5; ++ft) accO[qt][ft] = (v4f){0.f, 0.f, 0.f, 0.f};
#pragma unroll
    for (int s = 4; s < 8; ++s) {
      const int vcb = (s - 4) * 256;
      v8h pfr[2];
#pragma unroll
      for (int qt = 0; qt < 2; ++qt)
        pfr[qt] =
            *(const v8h*)&s_lds[(qt * 16 + lm) * SP + vcb + w * 32 + lg * 8];
#pragma unroll
      for (int ft = 0; ft < 5; ++ft) {
        v8h bfr = *(const v8h*)&kst[(ft * 16 + lm) * VP + w * 32 + lg * 8];
        accO[0][ft] = __builtin_amdgcn_mfma_f32_16x16x32_f16(
            pfr[0], bfr, accO[0][ft], 0, 0, 0);
        accO[1][ft] = __builtin_amdgcn_mfma_f32_16x16x32_f16(
            pfr[1], bfr, accO[1][ft], 0, 0, 0);
      }
      __syncthreads();  // V chunk consumers done
      if (s < 6) {
        lwriteV();
        gloadV(vt4, s - 2);
        __syncthreads();
      } else if (s == 6) {
        lwriteV();  // V3
        if (h < 7) gloadK(kbn, 0);
        __syncthreads();
      } else {
        if (h < 7) {
          lwriteK();  // K0 next head
          gloadK(kbn, 1);
          qstage(qkv + ((size_t)(b * 24 + h + 1) * NT + t0) * FP);
        }
        __syncthreads();
      }
    }
    // ---- O epilogue: cross-wave reduce via s_lds (P dead) ----
    float* ored = (float*)s_lds;  // [8][16][84]
#pragma unroll
    for (int qt = 0; qt < 2; ++qt) {
#pragma unroll
      for (int ft = 0; ft < 5; ++ft)
#pragma unroll
        for (int r = 0; r < 4; ++r)
          ored[(w * 16 + lg * 4 + r) * 84 + ft * 16 + lm] = accO[qt][ft][r];
      __syncthreads();
      for (int i = tid; i < 1280; i += 512) {
        int q = i / 80, f = i % 80;
        float ss = 0.f;
#pragma unroll
        for (int ww = 0; ww < 8; ++ww) ss += ored[(ww * 16 + q) * 84 + f];
        attn_out[((size_t)(b * 16 + h) * NT + t0 + qt * 16 + q) * NF + f] = ss;
      }
      __syncthreads();
    }
  }
  // ---- aw head-average write (register distribution) ----
#pragma unroll
  for (int s4 = 0; s4 < 4; ++s4)
#pragma unroll
    for (int tt = 0; tt < 2; ++tt)
#pragma unroll
      for (int qt = 0; qt < 2; ++qt)
#pragma unroll
        for (int r = 0; r < 4; ++r) {
          int row = qt * 16 + lg * 4 + r;
          int col = s4 * 256 + (w * 2 + tt) * 16 + lm;
          aw_avg[((size_t)b * NT + t0 + row) * NT + col] =
              avg[s4][tt][qt][r] * 0.125f;
        }
}

// ---------------------------------------------------------------------------
// Freq attention stage 1 (unchanged)
// ---------------------------------------------------------------------------
__global__ __launch_bounds__(64) void freq_qk_k(
    const _Float16* __restrict__ qkv, float* __restrict__ Cp) {
  __shared__ _Float16 qs[128 * 100];
  __shared__ _Float16 ks[128 * 100];
  const int tc = blockIdx.x, bh = blockIdx.y;
  const int b = bh >> 3, h = bh & 7;
  const int t0 = tc * 128;
  const _Float16* qb = qkv + ((size_t)(b * 24 + h) * NT + t0) * FP;
  const _Float16* kb = qkv + ((size_t)(b * 24 + 8 + h) * NT + t0) * FP;
  const int tid = threadIdx.x;
  for (int i = tid; i < 1536; i += 64) {
    int row = i / 12, c = i % 12;
    int4 vq = ((const int4*)qb)[i];
    int4 vk = ((const int4*)kb)[i];
    int2* dq = (int2*)&qs[row * 100 + c * 8];
    dq[0] = make_int2(vq.x, vq.y);
    dq[1] = make_int2(vq.z, vq.w);
    int2* dk = (int2*)&ks[row * 100 + c * 8];
    dk[0] = make_int2(vk.x, vk.y);
    dk[1] = make_int2(vk.z, vk.w);
  }
  __syncthreads();
  const int lg = tid >> 4, lm = tid & 15;
  v4f acc[5][5];
#pragma unroll
  for (int fr = 0; fr < 5; ++fr)
#pragma unroll
    for (int gc = 0; gc < 5; ++gc) acc[fr][gc] = (v4f){0.f, 0.f, 0.f, 0.f};
#pragma unroll
  for (int kk = 0; kk < 4; ++kk) {
    v8h afr[5];
#pragma unroll
    for (int fr = 0; fr < 5; ++fr)
#pragma unroll
      for (int j = 0; j < 8; ++j)
        afr[fr][j] = qs[(kk * 32 + lg * 8 + j) * 100 + fr * 16 + lm];
#pragma unroll
    for (int gc = 0; gc < 5; ++gc) {
      v8h bfr;
#pragma unroll
      for (int j = 0; j < 8; ++j)
        bfr[j] = ks[(kk * 32 + lg * 8 + j) * 100 + gc * 16 + lm];
#pragma unroll
      for (int fr = 0; fr < 5; ++fr)
        acc[fr][gc] = __builtin_amdgcn_mfma_f32_16x16x32_f16(afr[fr], bfr,
                                                             acc[fr][gc], 0,
                                                             0, 0);
    }
  }
  float* cpb = Cp + ((size_t)bh * 8 + tc) * 6400;
#pragma unroll
  for (int fr = 0; fr < 5; ++fr)
#pragma unroll
    for (int gc = 0; gc < 5; ++gc)
#pragma unroll
      for (int r = 0; r < 4; ++r)
        cpb[(fr * 16 + lg * 4 + r) * 80 + gc * 16 + lm] = acc[fr][gc][r];
}

// ---------------------------------------------------------------------------
// Freq attention stage 2 (unchanged)
// ---------------------------------------------------------------------------
__global__ __launch_bounds__(128) void freq_sm_k(const float* __restrict__ Cp,
                                                 _Float16* __restrict__ P) {
  const int bh = blockIdx.x;
  const int f = threadIdx.x;
  if (f >= 80) return;
  float c[80];
#pragma unroll
  for (int g = 0; g < 80; ++g) c[g] = 0.f;
  const float* base = Cp + (size_t)bh * 8 * 6400 + f * 80;
#pragma unroll
  for (int tc = 0; tc < 8; ++tc) {
    const float4* p4 = (const float4*)(base + tc * 6400);
#pragma unroll
    for (int g4 = 0; g4 < 20; ++g4) {
      float4 v = p4[g4];
      c[g4 * 4 + 0] += v.x;
      c[g4 * 4 + 1] += v.y;
      c[g4 * 4 + 2] += v.z;
      c[g4 * 4 + 3] += v.w;
    }
  }
  float m = -1e30f;
#pragma unroll
  for (int g = 0; g < 80; ++g) m = fmaxf(m, c[g]);
  float d = 0.f;
#pragma unroll
  for (int g = 0; g < 80; ++g) {
    float e = __expf(c[g] - m);
    d += e;
    c[g] = e;
  }
  float inv = 1.f / d;
  _Float16* pb = P + (size_t)bh * 80 * 96 + (size_t)f * 96;
#pragma unroll
  for (int c8 = 0; c8 < 10; ++c8) {
    v8h v;
#pragma unroll
    for (int j = 0; j < 8; ++j) v[j] = (_Float16)(c[c8 * 8 + j] * inv);
    *(v8h*)(pb + c8 * 8) = v;
  }
  v8h z = (v8h)(_Float16)0.f;
  *(v8h*)(pb + 80) = z;
  *(v8h*)(pb + 88) = z;
}

// ---------------------------------------------------------------------------
// Freq attention stage 3 (unchanged)
// ---------------------------------------------------------------------------
__global__ __launch_bounds__(256) void freq_pv_k(
    const _Float16* __restrict__ qkv, const _Float16* __restrict__ P,
    float* __restrict__ attn_out) {
  __shared__ _Float16 vs[128 * 104];
  __shared__ _Float16 ps[80 * 104];
  const int tc = blockIdx.x, bh = blockIdx.y;
  const int b = bh >> 3, h = bh & 7;
  const int t0 = tc * 128;
  const _Float16* vb = qkv + ((size_t)(b * 24 + 16 + h) * NT + t0) * FP;
  const _Float16* pb = P + (size_t)bh * 80 * 96;
  const int tid = threadIdx.x;
  for (int i = tid; i < 1536; i += 256) {
    int row = i / 12, c = i % 12;
    *(int4*)&vs[row * 104 + c * 8] = ((const int4*)vb)[i];
  }
  for (int i = tid; i < 960; i += 256) {
    int row = i / 12, c = i % 12;
    *(int4*)&ps[row * 104 + c * 8] = ((const int4*)pb)[i];
  }
  __syncthreads();
  const int w = tid >> 6, l = tid & 63, lg = l >> 4, lm = l & 15;
  v8h bfr[5][3];
#pragma unroll
  for (int fc = 0; fc < 5; ++fc)
#pragma unroll
    for (int kk = 0; kk < 3; ++kk)
      bfr[fc][kk] = *(const v8h*)&ps[(fc * 16 + lm) * 104 + kk * 32 + lg * 8];
#pragma unroll
  for (int tt2 = 0; tt2 < 2; ++tt2) {
    const int tt = w + tt2 * 4;
    v8h afr[3];
#pragma unroll
    for (int kk = 0; kk < 3; ++kk)
      afr[kk] = *(const v8h*)&vs[(tt * 16 + lm) * 104 + kk * 32 + lg * 8];
    float* ob =
        attn_out + ((size_t)(b * 16 + 8 + h) * NT + t0 + tt * 16) * NF;
#pragma unroll
    for (int fc = 0; fc < 5; ++fc) {
      v4f acc = (v4f){0.f, 0.f, 0.f, 0.f};
#pragma unroll
      for (int kk = 0; kk < 3; ++kk)
        acc = __builtin_amdgcn_mfma_f32_16x16x32_f16(afr[kk], bfr[fc][kk],
                                                     acc, 0, 0, 0);
#pragma unroll
      for (int r = 0; r < 4; ++r)
        ob[(lg * 4 + r) * NF + fc * 16 + lm] = acc[r];
    }
  }
}

// BN + relu: read fp16 y, write final fp32 out
__global__ __launch_bounds__(256) void bn_apply_out_k(
    const _Float16* __restrict__ y, const float* __restrict__ stats,
    const float* __restrict__ go, const float* __restrict__ bo,
    float* __restrict__ out) {
  const size_t n8 = OUT_ELEMS / 8;
  const size_t stride = (size_t)gridDim.x * blockDim.x;
  for (size_t idx = (size_t)blockIdx.x * blockDim.x + threadIdx.x; idx < n8;
       idx += stride) {
    int c = (int)((idx / (NT * NF / 8)) % 16);
    float g = go[c], be = bo[c];
    float mean = stats[c * 2 + 0], invstd = stats[c * 2 + 1];
    v8h v = ((const v8h*)y)[idx];
    float4 o0, o1;
    o0.x = fmaxf(((float)v[0] - mean) * invstd * g + be, 0.f);
    o0.y = fmaxf(((float)v[1] - mean) * invstd * g + be, 0.f);
    o0.z = fmaxf(((float)v[2] - mean) * invstd * g + be, 0.f);
    o0.w = fmaxf(((float)v[3] - mean) * invstd * g + be, 0.f);
    o1.x = fmaxf(((float)v[4] - mean) * invstd * g + be, 0.f);
    o1.y = fmaxf(((float)v[5] - mean) * invstd * g + be, 0.f);
    o1.z = fmaxf(((float)v[6] - mean) * invstd * g + be, 0.f);
    o1.w = fmaxf(((float)v[7] - mean) * invstd * g + be, 0.f);
    ((float4*)out)[idx * 2] = o0;
    ((float4*)out)[idx * 2 + 1] = o1;
  }
}

// ---------------------------------------------------------------------------
extern "C" void kernel_launch(void* const* d_in, const int* in_sizes, int n_in,
                              void* d_out, int out_size, void* d_ws,
                              size_t ws_size, hipStream_t stream) {
  const float* x = (const float*)d_in[0];
  const float* w_in = (const float*)d_in[1];
  const float* b_in = (const float*)d_in[2];
  const float* w_out = (const float*)d_in[3];
  const float* b_out = (const float*)d_in[4];
  const float* gq = (const float*)d_in[5];
  const float* bq = (const float*)d_in[6];
  const float* gk = (const float*)d_in[7];
  const float* bk = (const float*)d_in[8];
  const float* gv = (const float*)d_in[9];
  const float* bv = (const float*)d_in[10];
  const float* go = (const float*)d_in[11];
  const float* bo = (const float*)d_in[12];

  float* out = (float*)d_out;                    // (16,16,1024,80) fp32
  float* aw = out + OUT_ELEMS;                   // (16,1024,1024) fp32
  char* wsb = (char*)d_ws;
  _Float16* qkvb = (_Float16*)wsb;               // [0, 75.5 MB)
  _Float16* yh = (_Float16*)wsb;                 // fp16 y aliases dead qkvb
  _Float16* vTb = (_Float16*)(wsb + 75497472);   // 21 MB vT (dead before Cp)
  float* Cp = (float*)(wsb + 75497472);          // 26.2 MB freq partials
  _Float16* Pf = (_Float16*)(wsb + 101711872);   // 1.97 MB freq probs
  float* pstats = (float*)(wsb + 119537664);     // 2*24*1024 floats (196 KB)
  float* stats1 = pstats + 49152;
  float* stats2 = stats1 + 48;

  // conv_in (fused channels-last staging from fp32 NCHW) + BN partials
  conv_mfma_k<2, FP, true, true>
      <<<dim3(64, 16), 512, 0, stream>>>(x, w_in, b_in, qkvb, pstats, 24);
  bn_finalize2_k<<<24, 256, 0, stream>>>(pstats, stats1, 24);
  bn_apply_qk_k<<<2048, 256, 0, stream>>>(qkvb, stats1, gq, bq, gk, bk);
  vtrans_bn_k<<<dim3(8, 128), 256, 0, stream>>>(qkvb, stats1, gv, bv, vTb);
  time_attn_k<<<dim3(32, 16), 512, 0, stream>>>(qkvb, vTb, out, aw);
  freq_qk_k<<<dim3(8, 128), 64, 0, stream>>>(qkvb, Cp);
  freq_sm_k<<<128, 128, 0, stream>>>(Cp, Pf);
  freq_pv_k<<<dim3(8, 128), 256, 0, stream>>>(qkvb, Pf, out);
  // conv_out (fused channels-last staging from fp32 attn) + BN partials
  conv_mfma_k<1, NF, false, false>
      <<<dim3(64, 16), 512, 0, stream>>>(out, w_out, b_out, yh, pstats, 16);
  bn_finalize2_k<<<16, 256, 0, stream>>>(pstats, stats2, 16);
  bn_apply_out_k<<<2048, 256, 0, stream>>>(yh, stats2, go, bo, out);
}

// Round 16
// 391.431 us; speedup vs baseline: 1.2302x; 1.2302x over previous
//
#include <hip/hip_runtime.h>
#include <cstdint>
#include <cstddef>

// Problem constants: B=16, E=16, T=1024, F=80, H=8, 3H=24 qkv channels
#define NB 16
#define NT 1024
#define NF 80
#define NH 8
#define FP 96   // qkv f padded to 96 (3 x K=32 MFMA steps); pad is zero
#define FS 84   // channels-last padded f-sites (site s <-> f = s-1; 0,81..83 zero)
#define SP 1032 // time_attn S-strip row stride (fp16)
#define KP 108  // time_attn kst/q_lds K-row stride (fp16)
#define VP 264  // time_attn V^T-chunk row stride (fp16): 80 rows x 256 t

typedef _Float16 v8h __attribute__((ext_vector_type(8)));  // 8 fp16 (4 VGPRs)
typedef _Float16 v4h __attribute__((ext_vector_type(4)));  // 4 fp16 (8 B)
typedef _Float16 v2h __attribute__((ext_vector_type(2)));  // 2 fp16 (4 B)
typedef float v4f __attribute__((ext_vector_type(4)));     // mfma f32x4 acc

static const size_t OUT_ELEMS = (size_t)NB * 16 * NT * NF;  // 20,971,520

// ---------------------------------------------------------------------------
// conv3x3 SAME as MFMA implicit GEMM, reading fp32 NCHW input DIRECTLY
// (channels-last transpose fused into the axt staging). Emits per-block
// per-channel partial (sum, sumsq) for downstream BN.
// ---------------------------------------------------------------------------
template <int OCT, int OSTRIDE, bool QSCALE, bool PADOUT>
__global__ __launch_bounds__(512) void conv_mfma_k(
    const float* __restrict__ src, const float* __restrict__ w,
    const float* __restrict__ bias, _Float16* __restrict__ out,
    float* __restrict__ pstats, int CO) {
  __shared__ _Float16 axt[18][FS * 16];            // 48.4 KB
  __shared__ _Float16 wlds[3][2][OCT * 16][32];
  __shared__ float blds[32];
  __shared__ float wsum[8][OCT][16], wsq[8][OCT][16];
  const int b = blockIdx.y, t0 = blockIdx.x * 16;
  const int tid = threadIdx.x;
  const int NW = 3 * 2 * OCT * 16 * 32;
  for (int i = tid; i < NW; i += 512) {
    int kk = i % 32;
    int oc = (i / 32) % (OCT * 16);
    int ck = (i / (32 * OCT * 16)) % 2;
    int kt = i / (64 * OCT * 16);
    int kg = ck * 32 + kk;
    float v = 0.f;
    if (oc < CO && kg < 48) {
      int c = kg & 15, kf = kg >> 4;
      v = w[((oc * 16 + c) * 3 + kt) * 3 + kf];
      if (QSCALE && oc < 8) v *= 0.25f;
    }
    wlds[kt][ck][oc][kk] = (_Float16)v;
  }
  if (tid < 32) {
    float v = (tid < CO) ? bias[tid] : 0.f;
    if (QSCALE && tid < 8) v *= 0.25f;
    blds[tid] = v;
  }
  // ---- zero pad sites 0, 81..83 ----
  for (int i = tid; i < 144; i += 512) {
    int r = i / 8, j = i % 8;
    int sidx = j >> 1, half = j & 1;
    int site = (sidx == 0) ? 0 : 80 + sidx;
    *(v8h*)&axt[r][site * 16 + half * 8] = (v8h)(_Float16)0.f;
  }
  // ---- stage 18 rows channels-last from fp32 NCHW (cl_k fused) ----
  for (int i = tid; i < 18 * 80; i += 512) {
    int r = i / 80, f = i % 80;
    int t = t0 + r - 1;
    v8h lo = (v8h)(_Float16)0.f, hi = (v8h)(_Float16)0.f;
    if (t >= 0 && t < NT) {
#pragma unroll
      for (int c = 0; c < 8; ++c)
        lo[c] = (_Float16)src[((size_t)(b * 16 + c) * NT + t) * NF + f];
#pragma unroll
      for (int c = 0; c < 8; ++c)
        hi[c] = (_Float16)src[((size_t)(b * 16 + 8 + c) * NT + t) * NF + f];
    }
    *(v8h*)&axt[r][(f + 1) * 16] = lo;
    *(v8h*)&axt[r][(f + 1) * 16 + 8] = hi;
  }
  __syncthreads();
  const int wv = tid >> 6, l = tid & 63, lg = l >> 4, lm = l & 15;
  v8h bfr[3][2][OCT];
#pragma unroll
  for (int kt = 0; kt < 3; ++kt)
#pragma unroll
    for (int ck = 0; ck < 2; ++ck)
#pragma unroll
      for (int ot = 0; ot < OCT; ++ot)
        bfr[kt][ck][ot] = *(const v8h*)&wlds[kt][ck][ot * 16 + lm][lg * 8];
  float s1[OCT], s2[OCT];
#pragma unroll
  for (int ot = 0; ot < OCT; ++ot) { s1[ot] = 0.f; s2[ot] = 0.f; }
#pragma unroll
  for (int li = 0; li < 2; ++li) {
    const int lt = wv * 2 + li;
    const int tt = t0 + lt;
#pragma unroll
    for (int f0 = 0; f0 < 80; f0 += 16) {
      v4f acc[OCT];
#pragma unroll
      for (int ot = 0; ot < OCT; ++ot) acc[ot] = (v4f){0.f, 0.f, 0.f, 0.f};
#pragma unroll
      for (int kt = 0; kt < 3; ++kt)
#pragma unroll
        for (int ck = 0; ck < 2; ++ck) {
          v8h afr =
              *(const v8h*)&axt[lt + kt][(f0 + lm) * 16 + ck * 32 + lg * 8];
#pragma unroll
          for (int ot = 0; ot < OCT; ++ot)
            acc[ot] = __builtin_amdgcn_mfma_f32_16x16x32_f16(
                afr, bfr[kt][ck][ot], acc[ot], 0, 0, 0);
        }
#pragma unroll
      for (int ot = 0; ot < OCT; ++ot) {
        int oc = ot * 16 + lm;
        if (oc < CO) {
          float bv = blds[oc];
          v4h o;
#pragma unroll
          for (int r = 0; r < 4; ++r) {
            float v = acc[ot][r] + bv;
            s1[ot] += v;
            s2[ot] += v * v;
            o[r] = (_Float16)v;
          }
          *(v4h*)(out + ((size_t)(b * CO + oc) * NT + tt) * OSTRIDE + f0 +
                  lg * 4) = o;
        }
      }
    }
  }
  if constexpr (PADOUT) {
    for (int i = tid; i < CO * 16 * 2; i += 512) {
      int oc = i / 32, lt2 = (i / 2) % 16, half = i & 1;
      int4 z = {0, 0, 0, 0};
      ((int4*)(out + ((size_t)(b * CO + oc) * NT + t0 + lt2) * OSTRIDE +
               80))[half] = z;
    }
  }
#pragma unroll
  for (int ot = 0; ot < OCT; ++ot) {
    float a = s1[ot], b2 = s2[ot];
    a += __shfl_xor(a, 16);
    a += __shfl_xor(a, 32);
    b2 += __shfl_xor(b2, 16);
    b2 += __shfl_xor(b2, 32);
    if (l < 16) { wsum[wv][ot][lm] = a; wsq[wv][ot][lm] = b2; }
  }
  __syncthreads();
  if (tid < CO) {
    int ot = tid >> 4, lmm = tid & 15;
    float a = 0.f, b2 = 0.f;
#pragma unroll
    for (int w2 = 0; w2 < 8; ++w2) { a += wsum[w2][ot][lmm]; b2 += wsq[w2][ot][lmm]; }
    int bid = blockIdx.y * 64 + blockIdx.x;  // grid (64,16) -> 1024 blocks
    pstats[tid * 1024 + bid] = a;
    pstats[(CO + tid) * 1024 + bid] = b2;
  }
}

// ---------------------------------------------------------------------------
// BN finalize from conv partials: grid = C blocks x 256 threads.
// ---------------------------------------------------------------------------
__global__ __launch_bounds__(256) void bn_finalize2_k(
    const float* __restrict__ pstats, float* __restrict__ stats, int C) {
  const int c = blockIdx.x;
  float a = 0.f, b2 = 0.f;
  for (int i = threadIdx.x; i < 1024; i += 256) {
    a += pstats[c * 1024 + i];
    b2 += pstats[(C + c) * 1024 + i];
  }
  __shared__ float rs[256], rs2[256];
  rs[threadIdx.x] = a;
  rs2[threadIdx.x] = b2;
  __syncthreads();
  for (int off = 128; off > 0; off >>= 1) {
    if ((int)threadIdx.x < off) {
      rs[threadIdx.x] += rs[threadIdx.x + off];
      rs2[threadIdx.x] += rs2[threadIdx.x + off];
    }
    __syncthreads();
  }
  if (threadIdx.x == 0) {
    const float N = 16.0f * (float)(NT * NF);
    float mean = rs[0] / N;
    float var = rs2[0] / N - mean * mean;
    stats[c * 2 + 0] = mean;
    stats[c * 2 + 1] = rsqrtf(var + 1e-5f);
  }
}

// BN affine + relu in place on fp16 qkv -- q,k channels only (v handled by
// vtrans_bn_k).
__global__ __launch_bounds__(256) void bn_apply_qk_k(
    _Float16* __restrict__ qkv, const float* __restrict__ stats,
    const float* __restrict__ gq, const float* __restrict__ bq,
    const float* __restrict__ gk, const float* __restrict__ bk) {
  const size_t n8 = (size_t)NB * 16 * NT * 12;
  const size_t stride = (size_t)gridDim.x * blockDim.x;
  for (size_t idx = (size_t)blockIdx.x * blockDim.x + threadIdx.x; idx < n8;
       idx += stride) {
    int fc = (int)(idx % 12);
    if (fc >= 10) continue;  // f 80..95 stays zero
    int ch = (int)((idx / (NT * 12)) % 16);
    int b = (int)(idx / (16 * NT * 12));
    size_t rest = idx % (NT * 12);
    size_t v8idx = ((size_t)(b * 24 + ch) * NT * 12) + rest;
    float g, be;
    if (ch < 8) { g = gq[ch]; be = bq[ch]; }
    else { g = gk[ch - 8]; be = bk[ch - 8]; }
    float mean = stats[ch * 2 + 0], invstd = stats[ch * 2 + 1];
    v8h v = ((v8h*)qkv)[v8idx];
#pragma unroll
    for (int j = 0; j < 8; ++j) {
      float f = (float)v[j];
      f = fmaxf((f - mean) * invstd * g + be, 0.f);
      v[j] = (_Float16)f;
    }
    ((v8h*)qkv)[v8idx] = v;
  }
}

// ---------------------------------------------------------------------------
// V: BN+relu (write back normalized v to qkv) + transpose -> vT [bh][80][1024]
// ---------------------------------------------------------------------------
__global__ __launch_bounds__(256) void vtrans_bn_k(
    _Float16* __restrict__ qkv, const float* __restrict__ stats,
    const float* __restrict__ gv, const float* __restrict__ bv,
    _Float16* __restrict__ vT) {
  __shared__ _Float16 tile[128 * 100];  // 25.6 KB
  const int tc = blockIdx.x, bh = blockIdx.y;
  const int b = bh >> 3, h = bh & 7;
  const int t0 = tc * 128;
  _Float16* src = qkv + ((size_t)(b * 24 + 16 + h) * NT + t0) * FP;
  const int tid = threadIdx.x;
  const float mean = stats[(16 + h) * 2 + 0];
  const float invstd = stats[(16 + h) * 2 + 1];
  const float g = gv[h], be = bv[h];
  for (int i = tid; i < 1536; i += 256) {
    int row = i / 12, c = i % 12;
    v8h v = *(v8h*)(src + (size_t)row * FP + c * 8);
    if (c < 10) {  // f 80..95 stays zero
#pragma unroll
      for (int j = 0; j < 8; ++j) {
        float f = (float)v[j];
        f = fmaxf((f - mean) * invstd * g + be, 0.f);
        v[j] = (_Float16)f;
      }
      *(v8h*)(src + (size_t)row * FP + c * 8) = v;  // normalized v back
    }
    int2* d = (int2*)&tile[row * 100 + c * 8];
    int4 vi = __builtin_bit_cast(int4, v);
    d[0] = make_int2(vi.x, vi.y);
    d[1] = make_int2(vi.z, vi.w);
  }
  __syncthreads();
  _Float16* dst = vT + (size_t)bh * 80 * NT + t0;
  for (int i = tid; i < 1280; i += 256) {
    int f = i / 16, c8 = i % 16;
    v8h v;
#pragma unroll
    for (int j = 0; j < 8; ++j) v[j] = tile[(c8 * 8 + j) * 100 + f];
    *(v8h*)(dst + (size_t)f * NT + c8 * 8) = v;
  }
}

// ---------------------------------------------------------------------------
// Time attention, MFMA fp16 (R13 verbatim -- measured 204 us).
// Block = (32-query strip, b), 512 threads. Swapped QK (A=K, B=Q) with v4h
// S-writes; fused single-pass softmax; PV from V^T chunks ([80][VP]).
// ---------------------------------------------------------------------------
__global__ __launch_bounds__(512) void time_attn_k(
    const _Float16* __restrict__ qkv, const _Float16* __restrict__ vT,
    float* __restrict__ attn_out, float* __restrict__ aw_avg) {
  __shared__ _Float16 s_lds[32 * SP];   // 66 KB; reused as ored fp32
  __shared__ _Float16 q_lds[32 * KP];   // 6.9 KB
  __shared__ _Float16 kst[256 * KP];    // 55.3 KB: K chunks / V^T chunks union
  __shared__ float inv_lds[32];
  const int b = blockIdx.y, t0 = blockIdx.x * 32;
  const int tid = threadIdx.x;
  const int w = tid >> 6, l = tid & 63, lg = l >> 4, lm = l & 15;
  const int grp = tid >> 5, lane = tid & 31;
  float avg[2][32];
#pragma unroll
  for (int rr = 0; rr < 2; ++rr)
#pragma unroll
    for (int k = 0; k < 32; ++k) avg[rr][k] = 0.f;

  int4 rb[6];
  auto gloadK = [&](const _Float16* base, int chunk) {
    const int4* src = (const int4*)(base + (size_t)chunk * 256 * FP);
#pragma unroll
    for (int u = 0; u < 6; ++u) rb[u] = src[tid + u * 512];
  };
  auto lwriteK = [&]() {
#pragma unroll
    for (int u = 0; u < 6; ++u) {
      int i = tid + u * 512, row = i / 12, j = i % 12;
      int2* d = (int2*)&kst[row * KP + j * 8];
      d[0] = make_int2(rb[u].x, rb[u].y);
      d[1] = make_int2(rb[u].z, rb[u].w);
    }
  };
  auto gloadV = [&](const int4* vt4, int chunk) {
#pragma unroll
    for (int u = 0; u < 5; ++u) {
      int i = tid + u * 512, row = i >> 5, c = i & 31;
      rb[u] = vt4[row * 128 + chunk * 32 + c];
    }
  };
  auto lwriteV = [&]() {
#pragma unroll
    for (int u = 0; u < 5; ++u) {
      int i = tid + u * 512, row = i >> 5, c = i & 31;
      *(int4*)&kst[row * VP + c * 8] = rb[u];
    }
  };

  // preload first head's K chunk 0
  gloadK(qkv + (size_t)(b * 24 + 8) * NT * FP, 0);

  for (int h = 0; h < NH; ++h) {
    const _Float16* qb = qkv + ((size_t)(b * 24 + h) * NT + t0) * FP;
    const _Float16* kb = qkv + (size_t)(b * 24 + 8 + h) * NT * FP;
    const int4* vt4 = (const int4*)(vT + (size_t)(b * 8 + h) * 80 * NT);
    // head start: stage K0 + Q strip; prefetch K1
    int4 qreg = {0, 0, 0, 0};
    if (tid < 384) qreg = ((const int4*)qb)[tid];
    lwriteK();  // K0 -> kst
    if (tid < 384) {
      int row = tid / 12, j = tid % 12;
      int2* d = (int2*)&q_lds[row * KP + j * 8];
      d[0] = make_int2(qreg.x, qreg.y);
      d[1] = make_int2(qreg.z, qreg.w);
    }
    gloadK(kb, 1);
    __syncthreads();
    // B fragments (Q, col=query) for both query tiles
    v8h qfr[2][3];
#pragma unroll
    for (int qt = 0; qt < 2; ++qt)
#pragma unroll
      for (int kk = 0; kk < 3; ++kk) {
        v4h a0 = *(const v4h*)&q_lds[(qt * 16 + lm) * KP + kk * 32 + lg * 8];
        v4h a1 =
            *(const v4h*)&q_lds[(qt * 16 + lm) * KP + kk * 32 + lg * 8 + 4];
        qfr[qt][kk] = __builtin_shufflevector(a0, a1, 0, 1, 2, 3, 4, 5, 6, 7);
      }
    v4f accO[2][5];
#pragma unroll
    for (int qt = 0; qt < 2; ++qt)
#pragma unroll
      for (int ft = 0; ft < 5; ++ft) accO[qt][ft] = (v4f){0.f, 0.f, 0.f, 0.f};

    for (int s = 0; s < 8; ++s) {
      if (s == 4) {
        // ---- fused softmax on rows grp, grp+16: one read pass into regs ----
#pragma unroll
        for (int rr = 0; rr < 2; ++rr) {
          const int row = grp + rr * 16;
          _Float16* srow = &s_lds[row * SP];
          v2h ev[16];
          float m = -1e30f;
#pragma unroll
          for (int k = 0; k < 16; ++k) {
            ev[k] = *(const v2h*)&srow[lane * 2 + k * 64];
            m = fmaxf(m, fmaxf((float)ev[k][0], (float)ev[k][1]));
          }
#pragma unroll
          for (int mk = 16; mk; mk >>= 1) m = fmaxf(m, __shfl_xor(m, mk, 32));
          float d = 0.f;
#pragma unroll
          for (int k = 0; k < 16; ++k) {
            float e0 = __expf((float)ev[k][0] - m);
            float e1 = __expf((float)ev[k][1] - m);
            d += e0 + e1;
            v2h w2;
            w2[0] = (_Float16)e0;
            w2[1] = (_Float16)e1;
            ev[k] = w2;
            *(v2h*)&srow[lane * 2 + k * 64] = w2;
          }
#pragma unroll
          for (int mk = 16; mk; mk >>= 1) d += __shfl_xor(d, mk, 32);
          float inv = 1.f / d;
          if (lane == 0) inv_lds[row] = inv;
#pragma unroll
          for (int k = 0; k < 16; ++k) {
            avg[rr][2 * k] += (float)ev[k][0] * inv;
            avg[rr][2 * k + 1] += (float)ev[k][1] * inv;
          }
        }
        __syncthreads();  // P final before cross-row PV reads
      }
      if (s < 4) {
        // ---- QK on kst = K chunk s; swapped operands: A=K, B=Q ----
#pragma unroll
        for (int tt = 0; tt < 2; ++tt) {
          const int rowb = (w * 2 + tt) * 16;
          const int rbase = (rowb + lm) * KP;
          v8h kfr[3];
#pragma unroll
          for (int kk = 0; kk < 3; ++kk) {
            v4h b0 = *(const v4h*)&kst[rbase + kk * 32 + lg * 8];
            v4h b1 = *(const v4h*)&kst[rbase + kk * 32 + lg * 8 + 4];
            kfr[kk] = __builtin_shufflevector(b0, b1, 0, 1, 2, 3, 4, 5, 6, 7);
          }
          const int sc = s * 256 + rowb + lg * 4;
#pragma unroll
          for (int qt = 0; qt < 2; ++qt) {
            v4f acc = (v4f){0.f, 0.f, 0.f, 0.f};
#pragma unroll
            for (int kk = 0; kk < 3; ++kk)
              acc = __builtin_amdgcn_mfma_f32_16x16x32_f16(kfr[kk],
                                                           qfr[qt][kk], acc,
                                                           0, 0, 0);
            v4h o;
#pragma unroll
            for (int r = 0; r < 4; ++r) o[r] = (_Float16)acc[r];
            *(v4h*)&s_lds[(qt * 16 + lm) * SP + sc] = o;
          }
        }
      } else {
        // ---- PV on kst = V^T chunk s-4; contiguous B fragments ----
        const int vcb = (s - 4) * 256;
        v8h pfr[2];
#pragma unroll
        for (int qt = 0; qt < 2; ++qt)
          pfr[qt] =
              *(const v8h*)&s_lds[(qt * 16 + lm) * SP + vcb + w * 32 + lg * 8];
#pragma unroll
        for (int ft = 0; ft < 5; ++ft) {
          v8h bfr = *(const v8h*)&kst[(ft * 16 + lm) * VP + w * 32 + lg * 8];
          accO[0][ft] = __builtin_amdgcn_mfma_f32_16x16x32_f16(
              pfr[0], bfr, accO[0][ft], 0, 0, 0);
          accO[1][ft] = __builtin_amdgcn_mfma_f32_16x16x32_f16(
              pfr[1], bfr, accO[1][ft], 0, 0, 0);
        }
      }
      __syncthreads();  // all consumers of kst chunk s done
      if (s < 7) {
        if (s + 1 < 4) lwriteK(); else lwriteV();  // chunk s+1 -> kst
        int ns = s + 2;
        if (ns < 4) gloadK(kb, ns);
        else if (ns < 8) gloadV(vt4, ns - 4);
        else if (h < 7)
          gloadK(qkv + (size_t)(b * 24 + 8 + h + 1) * NT * FP, 0);
        __syncthreads();  // chunk s+1 visible
      }
    }
    // ---- O epilogue: scale by inv, cross-wave reduce via s_lds (P dead) ----
    float* ored = (float*)s_lds;  // [8][16][84]
#pragma unroll
    for (int qt = 0; qt < 2; ++qt) {
#pragma unroll
      for (int ft = 0; ft < 5; ++ft)
#pragma unroll
        for (int r = 0; r < 4; ++r)
          ored[(w * 16 + lg * 4 + r) * 84 + ft * 16 + lm] =
              accO[qt][ft][r] * inv_lds[qt * 16 + lg * 4 + r];
      __syncthreads();
      for (int i = tid; i < 1280; i += 512) {
        int q = i / 80, f = i % 80;
        float ss = 0.f;
#pragma unroll
        for (int ww = 0; ww < 8; ++ww) ss += ored[(ww * 16 + q) * 84 + f];
        attn_out[((size_t)(b * 16 + h) * NT + t0 + qt * 16 + q) * NF + f] = ss;
      }
      __syncthreads();
    }
  }
  // ---- aw head-average write (row-contiguous float2) ----
#pragma unroll
  for (int rr = 0; rr < 2; ++rr) {
    float* ab = aw_avg + ((size_t)b * NT + t0 + grp + rr * 16) * NT;
#pragma unroll
    for (int k = 0; k < 16; ++k) {
      float2 v2;
      v2.x = avg[rr][2 * k] * 0.125f;
      v2.y = avg[rr][2 * k + 1] * 0.125f;
      *(float2*)&ab[lane * 2 + k * 64] = v2;
    }
  }
}

// ---------------------------------------------------------------------------
// Freq attention stage 1 (unchanged)
// ---------------------------------------------------------------------------
__global__ __launch_bounds__(64) void freq_qk_k(
    const _Float16* __restrict__ qkv, float* __restrict__ Cp) {
  __shared__ _Float16 qs[128 * 100];
  __shared__ _Float16 ks[128 * 100];
  const int tc = blockIdx.x, bh = blockIdx.y;
  const int b = bh >> 3, h = bh & 7;
  const int t0 = tc * 128;
  const _Float16* qb = qkv + ((size_t)(b * 24 + h) * NT + t0) * FP;
  const _Float16* kb = qkv + ((size_t)(b * 24 + 8 + h) * NT + t0) * FP;
  const int tid = threadIdx.x;
  for (int i = tid; i < 1536; i += 64) {
    int row = i / 12, c = i % 12;
    int4 vq = ((const int4*)qb)[i];
    int4 vk = ((const int4*)kb)[i];
    int2* dq = (int2*)&qs[row * 100 + c * 8];
    dq[0] = make_int2(vq.x, vq.y);
    dq[1] = make_int2(vq.z, vq.w);
    int2* dk = (int2*)&ks[row * 100 + c * 8];
    dk[0] = make_int2(vk.x, vk.y);
    dk[1] = make_int2(vk.z, vk.w);
  }
  __syncthreads();
  const int lg = tid >> 4, lm = tid & 15;
  v4f acc[5][5];
#pragma unroll
  for (int fr = 0; fr < 5; ++fr)
#pragma unroll
    for (int gc = 0; gc < 5; ++gc) acc[fr][gc] = (v4f){0.f, 0.f, 0.f, 0.f};
#pragma unroll
  for (int kk = 0; kk < 4; ++kk) {
    v8h afr[5];
#pragma unroll
    for (int fr = 0; fr < 5; ++fr)
#pragma unroll
      for (int j = 0; j < 8; ++j)
        afr[fr][j] = qs[(kk * 32 + lg * 8 + j) * 100 + fr * 16 + lm];
#pragma unroll
    for (int gc = 0; gc < 5; ++gc) {
      v8h bfr;
#pragma unroll
      for (int j = 0; j < 8; ++j)
        bfr[j] = ks[(kk * 32 + lg * 8 + j) * 100 + gc * 16 + lm];
#pragma unroll
      for (int fr = 0; fr < 5; ++fr)
        acc[fr][gc] = __builtin_amdgcn_mfma_f32_16x16x32_f16(afr[fr], bfr,
                                                             acc[fr][gc], 0,
                                                             0, 0);
    }
  }
  float* cpb = Cp + ((size_t)bh * 8 + tc) * 6400;
#pragma unroll
  for (int fr = 0; fr < 5; ++fr)
#pragma unroll
    for (int gc = 0; gc < 5; ++gc)
#pragma unroll
      for (int r = 0; r < 4; ++r)
        cpb[(fr * 16 + lg * 4 + r) * 80 + gc * 16 + lm] = acc[fr][gc][r];
}

// ---------------------------------------------------------------------------
// Freq attention stage 2: cooperative coalesced partial-sum into LDS, then
// row softmax from LDS. Grid 128 (bh), 256 threads.
// ---------------------------------------------------------------------------
__global__ __launch_bounds__(256) void freq_sm_k(const float* __restrict__ Cp,
                                                 _Float16* __restrict__ P) {
  __shared__ float cs[6400];  // [80][80], 25.6 KB
  const int bh = blockIdx.x;
  const int tid = threadIdx.x;
  const float4* base = (const float4*)(Cp + (size_t)bh * 8 * 6400);
  for (int i = tid; i < 1600; i += 256) {
    float4 a = base[i];
#pragma unroll
    for (int tc = 1; tc < 8; ++tc) {
      float4 v = base[tc * 1600 + i];
      a.x += v.x;
      a.y += v.y;
      a.z += v.z;
      a.w += v.w;
    }
    ((float4*)cs)[i] = a;
  }
  __syncthreads();
  const int f = tid;
  if (f >= 80) return;
  const float* row = &cs[f * 80];
  float m = -1e30f;
#pragma unroll
  for (int g = 0; g < 80; ++g) m = fmaxf(m, row[g]);
  float d = 0.f;
  float e[80];
#pragma unroll
  for (int g = 0; g < 80; ++g) {
    e[g] = __expf(row[g] - m);
    d += e[g];
  }
  float inv = 1.f / d;
  _Float16* pb = P + (size_t)bh * 80 * 96 + (size_t)f * 96;
#pragma unroll
  for (int c8 = 0; c8 < 10; ++c8) {
    v8h v;
#pragma unroll
    for (int j = 0; j < 8; ++j) v[j] = (_Float16)(e[c8 * 8 + j] * inv);
    *(v8h*)(pb + c8 * 8) = v;
  }
  v8h z = (v8h)(_Float16)0.f;
  *(v8h*)(pb + 80) = z;
  *(v8h*)(pb + 88) = z;
}

// ---------------------------------------------------------------------------
// Freq attention stage 3 (unchanged)
// ---------------------------------------------------------------------------
__global__ __launch_bounds__(256) void freq_pv_k(
    const _Float16* __restrict__ qkv, const _Float16* __restrict__ P,
    float* __restrict__ attn_out) {
  __shared__ _Float16 vs[128 * 104];
  __shared__ _Float16 ps[80 * 104];
  const int tc = blockIdx.x, bh = blockIdx.y;
  const int b = bh >> 3, h = bh & 7;
  const int t0 = tc * 128;
  const _Float16* vb = qkv + ((size_t)(b * 24 + 16 + h) * NT + t0) * FP;
  const _Float16* pb = P + (size_t)bh * 80 * 96;
  const int tid = threadIdx.x;
  for (int i = tid; i < 1536; i += 256) {
    int row = i / 12, c = i % 12;
    *(int4*)&vs[row * 104 + c * 8] = ((const int4*)vb)[i];
  }
  for (int i = tid; i < 960; i += 256) {
    int row = i / 12, c = i % 12;
    *(int4*)&ps[row * 104 + c * 8] = ((const int4*)pb)[i];
  }
  __syncthreads();
  const int w = tid >> 6, l = tid & 63, lg = l >> 4, lm = l & 15;
  v8h bfr[5][3];
#pragma unroll
  for (int fc = 0; fc < 5; ++fc)
#pragma unroll
    for (int kk = 0; kk < 3; ++kk)
      bfr[fc][kk] = *(const v8h*)&ps[(fc * 16 + lm) * 104 + kk * 32 + lg * 8];
#pragma unroll
  for (int tt2 = 0; tt2 < 2; ++tt2) {
    const int tt = w + tt2 * 4;
    v8h afr[3];
#pragma unroll
    for (int kk = 0; kk < 3; ++kk)
      afr[kk] = *(const v8h*)&vs[(tt * 16 + lm) * 104 + kk * 32 + lg * 8];
    float* ob =
        attn_out + ((size_t)(b * 16 + 8 + h) * NT + t0 + tt * 16) * NF;
#pragma unroll
    for (int fc = 0; fc < 5; ++fc) {
      v4f acc = (v4f){0.f, 0.f, 0.f, 0.f};
#pragma unroll
      for (int kk = 0; kk < 3; ++kk)
        acc = __builtin_amdgcn_mfma_f32_16x16x32_f16(afr[kk], bfr[fc][kk],
                                                     acc, 0, 0, 0);
#pragma unroll
      for (int r = 0; r < 4; ++r)
        ob[(lg * 4 + r) * NF + fc * 16 + lm] = acc[r];
    }
  }
}

// BN + relu: read fp16 y, write final fp32 out
__global__ __launch_bounds__(256) void bn_apply_out_k(
    const _Float16* __restrict__ y, const float* __restrict__ stats,
    const float* __restrict__ go, const float* __restrict__ bo,
    float* __restrict__ out) {
  const size_t n8 = OUT_ELEMS / 8;
  const size_t stride = (size_t)gridDim.x * blockDim.x;
  for (size_t idx = (size_t)blockIdx.x * blockDim.x + threadIdx.x; idx < n8;
       idx += stride) {
    int c = (int)((idx / (NT * NF / 8)) % 16);
    float g = go[c], be = bo[c];
    float mean = stats[c * 2 + 0], invstd = stats[c * 2 + 1];
    v8h v = ((const v8h*)y)[idx];
    float4 o0, o1;
    o0.x = fmaxf(((float)v[0] - mean) * invstd * g + be, 0.f);
    o0.y = fmaxf(((float)v[1] - mean) * invstd * g + be, 0.f);
    o0.z = fmaxf(((float)v[2] - mean) * invstd * g + be, 0.f);
    o0.w = fmaxf(((float)v[3] - mean) * invstd * g + be, 0.f);
    o1.x = fmaxf(((float)v[4] - mean) * invstd * g + be, 0.f);
    o1.y = fmaxf(((float)v[5] - mean) * invstd * g + be, 0.f);
    o1.z = fmaxf(((float)v[6] - mean) * invstd * g + be, 0.f);
    o1.w = fmaxf(((float)v[7] - mean) * invstd * g + be, 0.f);
    ((float4*)out)[idx * 2] = o0;
    ((float4*)out)[idx * 2 + 1] = o1;
  }
}

// ---------------------------------------------------------------------------
extern "C" void kernel_launch(void* const* d_in, const int* in_sizes, int n_in,
                              void* d_out, int out_size, void* d_ws,
                              size_t ws_size, hipStream_t stream) {
  const float* x = (const float*)d_in[0];
  const float* w_in = (const float*)d_in[1];
  const float* b_in = (const float*)d_in[2];
  const float* w_out = (const float*)d_in[3];
  const float* b_out = (const float*)d_in[4];
  const float* gq = (const float*)d_in[5];
  const float* bq = (const float*)d_in[6];
  const float* gk = (const float*)d_in[7];
  const float* bk = (const float*)d_in[8];
  const float* gv = (const float*)d_in[9];
  const float* bv = (const float*)d_in[10];
  const float* go = (const float*)d_in[11];
  const float* bo = (const float*)d_in[12];

  float* out = (float*)d_out;                    // (16,16,1024,80) fp32
  float* aw = out + OUT_ELEMS;                   // (16,1024,1024) fp32
  char* wsb = (char*)d_ws;
  _Float16* qkvb = (_Float16*)wsb;               // [0, 75.5 MB)
  _Float16* yh = (_Float16*)wsb;                 // fp16 y aliases dead qkvb
  _Float16* vTb = (_Float16*)(wsb + 75497472);   // 21 MB vT (dead before Cp)
  float* Cp = (float*)(wsb + 75497472);          // 26.2 MB freq partials
  _Float16* Pf = (_Float16*)(wsb + 101711872);   // 1.97 MB freq probs
  float* pstats = (float*)(wsb + 119537664);     // 2*24*1024 floats (196 KB)
  float* stats1 = pstats + 49152;
  float* stats2 = stats1 + 48;

  // conv_in (fused channels-last staging from fp32 NCHW) + BN partials
  conv_mfma_k<2, FP, true, true>
      <<<dim3(64, 16), 512, 0, stream>>>(x, w_in, b_in, qkvb, pstats, 24);
  bn_finalize2_k<<<24, 256, 0, stream>>>(pstats, stats1, 24);
  bn_apply_qk_k<<<2048, 256, 0, stream>>>(qkvb, stats1, gq, bq, gk, bk);
  vtrans_bn_k<<<dim3(8, 128), 256, 0, stream>>>(qkvb, stats1, gv, bv, vTb);
  time_attn_k<<<dim3(32, 16), 512, 0, stream>>>(qkvb, vTb, out, aw);
  freq_qk_k<<<dim3(8, 128), 64, 0, stream>>>(qkvb, Cp);
  freq_sm_k<<<128, 256, 0, stream>>>(Cp, Pf);
  freq_pv_k<<<dim3(8, 128), 256, 0, stream>>>(qkvb, Pf, out);
  // conv_out (fused channels-last staging from fp32 attn) + BN partials
  conv_mfma_k<1, NF, false, false>
      <<<dim3(64, 16), 512, 0, stream>>>(out, w_out, b_out, yh, pstats, 16);
  bn_finalize2_k<<<16, 256, 0, stream>>>(pstats, stats2, 16);
  bn_apply_out_k<<<2048, 256, 0, stream>>>(yh, stats2, go, bo, out);
}

// Round 17
// 375.512 us; speedup vs baseline: 1.2824x; 1.0424x over previous
//
#include <hip/hip_runtime.h>
#include <cstdint>
#include <cstddef>

// Problem constants: B=16, E=16, T=1024, F=80, H=8, 3H=24 qkv channels
#define NB 16
#define NT 1024
#define NF 80
#define NH 8
#define FP 96   // qkv f padded to 96 (3 x K=32 MFMA steps); pad is zero
#define FS 84   // channels-last padded f-sites (site s <-> f = s-1; 0,81..83 zero)
#define SP 1032 // time_attn S-strip row stride (fp16)
#define KP 108  // time_attn kst/q_lds K-row stride (fp16)
#define VP 264  // time_attn V^T-chunk row stride (fp16): 80 rows x 256 t

typedef _Float16 v8h __attribute__((ext_vector_type(8)));  // 8 fp16 (4 VGPRs)
typedef _Float16 v4h __attribute__((ext_vector_type(4)));  // 4 fp16 (8 B)
typedef _Float16 v2h __attribute__((ext_vector_type(2)));  // 2 fp16 (4 B)
typedef float v4f __attribute__((ext_vector_type(4)));     // mfma f32x4 acc

static const size_t OUT_ELEMS = (size_t)NB * 16 * NT * NF;  // 20,971,520

// ---------------------------------------------------------------------------
// conv3x3 SAME as MFMA implicit GEMM, reading NCHW input (fp32 or fp16)
// DIRECTLY (channels-last transpose fused into the axt staging). Emits
// per-block per-channel partial (sum, sumsq) for downstream BN.
// ---------------------------------------------------------------------------
template <typename SRCT, int OCT, int OSTRIDE, bool QSCALE, bool PADOUT>
__global__ __launch_bounds__(512) void conv_mfma_k(
    const SRCT* __restrict__ src, const float* __restrict__ w,
    const float* __restrict__ bias, _Float16* __restrict__ out,
    float* __restrict__ pstats, int CO) {
  __shared__ _Float16 axt[18][FS * 16];            // 48.4 KB
  __shared__ _Float16 wlds[3][2][OCT * 16][32];
  __shared__ float blds[32];
  __shared__ float wsum[8][OCT][16], wsq[8][OCT][16];
  const int b = blockIdx.y, t0 = blockIdx.x * 16;
  const int tid = threadIdx.x;
  const int NW = 3 * 2 * OCT * 16 * 32;
  for (int i = tid; i < NW; i += 512) {
    int kk = i % 32;
    int oc = (i / 32) % (OCT * 16);
    int ck = (i / (32 * OCT * 16)) % 2;
    int kt = i / (64 * OCT * 16);
    int kg = ck * 32 + kk;
    float v = 0.f;
    if (oc < CO && kg < 48) {
      int c = kg & 15, kf = kg >> 4;
      v = w[((oc * 16 + c) * 3 + kt) * 3 + kf];
      if (QSCALE && oc < 8) v *= 0.25f;
    }
    wlds[kt][ck][oc][kk] = (_Float16)v;
  }
  if (tid < 32) {
    float v = (tid < CO) ? bias[tid] : 0.f;
    if (QSCALE && tid < 8) v *= 0.25f;
    blds[tid] = v;
  }
  // ---- zero pad sites 0, 81..83 ----
  for (int i = tid; i < 144; i += 512) {
    int r = i / 8, j = i % 8;
    int sidx = j >> 1, half = j & 1;
    int site = (sidx == 0) ? 0 : 80 + sidx;
    *(v8h*)&axt[r][site * 16 + half * 8] = (v8h)(_Float16)0.f;
  }
  // ---- stage 18 rows channels-last from NCHW (cl_k fused) ----
  for (int i = tid; i < 18 * 80; i += 512) {
    int r = i / 80, f = i % 80;
    int t = t0 + r - 1;
    v8h lo = (v8h)(_Float16)0.f, hi = (v8h)(_Float16)0.f;
    if (t >= 0 && t < NT) {
#pragma unroll
      for (int c = 0; c < 8; ++c)
        lo[c] = (_Float16)src[((size_t)(b * 16 + c) * NT + t) * NF + f];
#pragma unroll
      for (int c = 0; c < 8; ++c)
        hi[c] = (_Float16)src[((size_t)(b * 16 + 8 + c) * NT + t) * NF + f];
    }
    *(v8h*)&axt[r][(f + 1) * 16] = lo;
    *(v8h*)&axt[r][(f + 1) * 16 + 8] = hi;
  }
  __syncthreads();
  const int wv = tid >> 6, l = tid & 63, lg = l >> 4, lm = l & 15;
  v8h bfr[3][2][OCT];
#pragma unroll
  for (int kt = 0; kt < 3; ++kt)
#pragma unroll
    for (int ck = 0; ck < 2; ++ck)
#pragma unroll
      for (int ot = 0; ot < OCT; ++ot)
        bfr[kt][ck][ot] = *(const v8h*)&wlds[kt][ck][ot * 16 + lm][lg * 8];
  float s1[OCT], s2[OCT];
#pragma unroll
  for (int ot = 0; ot < OCT; ++ot) { s1[ot] = 0.f; s2[ot] = 0.f; }
#pragma unroll
  for (int li = 0; li < 2; ++li) {
    const int lt = wv * 2 + li;
    const int tt = t0 + lt;
#pragma unroll
    for (int f0 = 0; f0 < 80; f0 += 16) {
      v4f acc[OCT];
#pragma unroll
      for (int ot = 0; ot < OCT; ++ot) acc[ot] = (v4f){0.f, 0.f, 0.f, 0.f};
#pragma unroll
      for (int kt = 0; kt < 3; ++kt)
#pragma unroll
        for (int ck = 0; ck < 2; ++ck) {
          v8h afr =
              *(const v8h*)&axt[lt + kt][(f0 + lm) * 16 + ck * 32 + lg * 8];
#pragma unroll
          for (int ot = 0; ot < OCT; ++ot)
            acc[ot] = __builtin_amdgcn_mfma_f32_16x16x32_f16(
                afr, bfr[kt][ck][ot], acc[ot], 0, 0, 0);
        }
#pragma unroll
      for (int ot = 0; ot < OCT; ++ot) {
        int oc = ot * 16 + lm;
        if (oc < CO) {
          float bv = blds[oc];
          v4h o;
#pragma unroll
          for (int r = 0; r < 4; ++r) {
            float v = acc[ot][r] + bv;
            s1[ot] += v;
            s2[ot] += v * v;
            o[r] = (_Float16)v;
          }
          *(v4h*)(out + ((size_t)(b * CO + oc) * NT + tt) * OSTRIDE + f0 +
                  lg * 4) = o;
        }
      }
    }
  }
  if constexpr (PADOUT) {
    for (int i = tid; i < CO * 16 * 2; i += 512) {
      int oc = i / 32, lt2 = (i / 2) % 16, half = i & 1;
      int4 z = {0, 0, 0, 0};
      ((int4*)(out + ((size_t)(b * CO + oc) * NT + t0 + lt2) * OSTRIDE +
               80))[half] = z;
    }
  }
#pragma unroll
  for (int ot = 0; ot < OCT; ++ot) {
    float a = s1[ot], b2 = s2[ot];
    a += __shfl_xor(a, 16);
    a += __shfl_xor(a, 32);
    b2 += __shfl_xor(b2, 16);
    b2 += __shfl_xor(b2, 32);
    if (l < 16) { wsum[wv][ot][lm] = a; wsq[wv][ot][lm] = b2; }
  }
  __syncthreads();
  if (tid < CO) {
    int ot = tid >> 4, lmm = tid & 15;
    float a = 0.f, b2 = 0.f;
#pragma unroll
    for (int w2 = 0; w2 < 8; ++w2) { a += wsum[w2][ot][lmm]; b2 += wsq[w2][ot][lmm]; }
    int bid = blockIdx.y * 64 + blockIdx.x;  // grid (64,16) -> 1024 blocks
    pstats[tid * 1024 + bid] = a;
    pstats[(CO + tid) * 1024 + bid] = b2;
  }
}

// ---------------------------------------------------------------------------
// BN finalize from conv partials: grid = C blocks x 256 threads.
// ---------------------------------------------------------------------------
__global__ __launch_bounds__(256) void bn_finalize2_k(
    const float* __restrict__ pstats, float* __restrict__ stats, int C) {
  const int c = blockIdx.x;
  float a = 0.f, b2 = 0.f;
  for (int i = threadIdx.x; i < 1024; i += 256) {
    a += pstats[c * 1024 + i];
    b2 += pstats[(C + c) * 1024 + i];
  }
  __shared__ float rs[256], rs2[256];
  rs[threadIdx.x] = a;
  rs2[threadIdx.x] = b2;
  __syncthreads();
  for (int off = 128; off > 0; off >>= 1) {
    if ((int)threadIdx.x < off) {
      rs[threadIdx.x] += rs[threadIdx.x + off];
      rs2[threadIdx.x] += rs2[threadIdx.x + off];
    }
    __syncthreads();
  }
  if (threadIdx.x == 0) {
    const float N = 16.0f * (float)(NT * NF);
    float mean = rs[0] / N;
    float var = rs2[0] / N - mean * mean;
    stats[c * 2 + 0] = mean;
    stats[c * 2 + 1] = rsqrtf(var + 1e-5f);
  }
}

// BN affine + relu in place on fp16 qkv -- q,k channels only (v handled by
// vtrans_bn_k).
__global__ __launch_bounds__(256) void bn_apply_qk_k(
    _Float16* __restrict__ qkv, const float* __restrict__ stats,
    const float* __restrict__ gq, const float* __restrict__ bq,
    const float* __restrict__ gk, const float* __restrict__ bk) {
  const size_t n8 = (size_t)NB * 16 * NT * 12;
  const size_t stride = (size_t)gridDim.x * blockDim.x;
  for (size_t idx = (size_t)blockIdx.x * blockDim.x + threadIdx.x; idx < n8;
       idx += stride) {
    int fc = (int)(idx % 12);
    if (fc >= 10) continue;  // f 80..95 stays zero
    int ch = (int)((idx / (NT * 12)) % 16);
    int b = (int)(idx / (16 * NT * 12));
    size_t rest = idx % (NT * 12);
    size_t v8idx = ((size_t)(b * 24 + ch) * NT * 12) + rest;
    float g, be;
    if (ch < 8) { g = gq[ch]; be = bq[ch]; }
    else { g = gk[ch - 8]; be = bk[ch - 8]; }
    float mean = stats[ch * 2 + 0], invstd = stats[ch * 2 + 1];
    v8h v = ((v8h*)qkv)[v8idx];
#pragma unroll
    for (int j = 0; j < 8; ++j) {
      float f = (float)v[j];
      f = fmaxf((f - mean) * invstd * g + be, 0.f);
      v[j] = (_Float16)f;
    }
    ((v8h*)qkv)[v8idx] = v;
  }
}

// ---------------------------------------------------------------------------
// V: BN+relu (write back normalized v to qkv) + transpose -> vT [bh][80][1024]
// ---------------------------------------------------------------------------
__global__ __launch_bounds__(256) void vtrans_bn_k(
    _Float16* __restrict__ qkv, const float* __restrict__ stats,
    const float* __restrict__ gv, const float* __restrict__ bv,
    _Float16* __restrict__ vT) {
  __shared__ _Float16 tile[128 * 100];  // 25.6 KB
  const int tc = blockIdx.x, bh = blockIdx.y;
  const int b = bh >> 3, h = bh & 7;
  const int t0 = tc * 128;
  _Float16* src = qkv + ((size_t)(b * 24 + 16 + h) * NT + t0) * FP;
  const int tid = threadIdx.x;
  const float mean = stats[(16 + h) * 2 + 0];
  const float invstd = stats[(16 + h) * 2 + 1];
  const float g = gv[h], be = bv[h];
  for (int i = tid; i < 1536; i += 256) {
    int row = i / 12, c = i % 12;
    v8h v = *(v8h*)(src + (size_t)row * FP + c * 8);
    if (c < 10) {  // f 80..95 stays zero
#pragma unroll
      for (int j = 0; j < 8; ++j) {
        float f = (float)v[j];
        f = fmaxf((f - mean) * invstd * g + be, 0.f);
        v[j] = (_Float16)f;
      }
      *(v8h*)(src + (size_t)row * FP + c * 8) = v;  // normalized v back
    }
    int2* d = (int2*)&tile[row * 100 + c * 8];
    int4 vi = __builtin_bit_cast(int4, v);
    d[0] = make_int2(vi.x, vi.y);
    d[1] = make_int2(vi.z, vi.w);
  }
  __syncthreads();
  _Float16* dst = vT + (size_t)bh * 80 * NT + t0;
  for (int i = tid; i < 1280; i += 256) {
    int f = i / 16, c8 = i % 16;
    v8h v;
#pragma unroll
    for (int j = 0; j < 8; ++j) v[j] = tile[(c8 * 8 + j) * 100 + f];
    *(v8h*)(dst + (size_t)f * NT + c8 * 8) = v;
  }
}

// ---------------------------------------------------------------------------
// Time attention, MFMA fp16 (R13 structure; attn output now fp16).
// Block = (32-query strip, b), 512 threads. Swapped QK (A=K, B=Q) with v4h
// S-writes; fused single-pass softmax; PV from V^T chunks ([80][VP]).
// ---------------------------------------------------------------------------
__global__ __launch_bounds__(512) void time_attn_k(
    const _Float16* __restrict__ qkv, const _Float16* __restrict__ vT,
    _Float16* __restrict__ attn_out, float* __restrict__ aw_avg) {
  __shared__ _Float16 s_lds[32 * SP];   // 66 KB; reused as ored fp32
  __shared__ _Float16 q_lds[32 * KP];   // 6.9 KB
  __shared__ _Float16 kst[256 * KP];    // 55.3 KB: K chunks / V^T chunks union
  __shared__ float inv_lds[32];
  const int b = blockIdx.y, t0 = blockIdx.x * 32;
  const int tid = threadIdx.x;
  const int w = tid >> 6, l = tid & 63, lg = l >> 4, lm = l & 15;
  const int grp = tid >> 5, lane = tid & 31;
  float avg[2][32];
#pragma unroll
  for (int rr = 0; rr < 2; ++rr)
#pragma unroll
    for (int k = 0; k < 32; ++k) avg[rr][k] = 0.f;

  int4 rb[6];
  auto gloadK = [&](const _Float16* base, int chunk) {
    const int4* src = (const int4*)(base + (size_t)chunk * 256 * FP);
#pragma unroll
    for (int u = 0; u < 6; ++u) rb[u] = src[tid + u * 512];
  };
  auto lwriteK = [&]() {
#pragma unroll
    for (int u = 0; u < 6; ++u) {
      int i = tid + u * 512, row = i / 12, j = i % 12;
      int2* d = (int2*)&kst[row * KP + j * 8];
      d[0] = make_int2(rb[u].x, rb[u].y);
      d[1] = make_int2(rb[u].z, rb[u].w);
    }
  };
  auto gloadV = [&](const int4* vt4, int chunk) {
#pragma unroll
    for (int u = 0; u < 5; ++u) {
      int i = tid + u * 512, row = i >> 5, c = i & 31;
      rb[u] = vt4[row * 128 + chunk * 32 + c];
    }
  };
  auto lwriteV = [&]() {
#pragma unroll
    for (int u = 0; u < 5; ++u) {
      int i = tid + u * 512, row = i >> 5, c = i & 31;
      *(int4*)&kst[row * VP + c * 8] = rb[u];
    }
  };

  // preload first head's K chunk 0
  gloadK(qkv + (size_t)(b * 24 + 8) * NT * FP, 0);

  for (int h = 0; h < NH; ++h) {
    const _Float16* qb = qkv + ((size_t)(b * 24 + h) * NT + t0) * FP;
    const _Float16* kb = qkv + (size_t)(b * 24 + 8 + h) * NT * FP;
    const int4* vt4 = (const int4*)(vT + (size_t)(b * 8 + h) * 80 * NT);
    // head start: stage K0 + Q strip; prefetch K1
    int4 qreg = {0, 0, 0, 0};
    if (tid < 384) qreg = ((const int4*)qb)[tid];
    lwriteK();  // K0 -> kst
    if (tid < 384) {
      int row = tid / 12, j = tid % 12;
      int2* d = (int2*)&q_lds[row * KP + j * 8];
      d[0] = make_int2(qreg.x, qreg.y);
      d[1] = make_int2(qreg.z, qreg.w);
    }
    gloadK(kb, 1);
    __syncthreads();
    // B fragments (Q, col=query) for both query tiles
    v8h qfr[2][3];
#pragma unroll
    for (int qt = 0; qt < 2; ++qt)
#pragma unroll
      for (int kk = 0; kk < 3; ++kk) {
        v4h a0 = *(const v4h*)&q_lds[(qt * 16 + lm) * KP + kk * 32 + lg * 8];
        v4h a1 =
            *(const v4h*)&q_lds[(qt * 16 + lm) * KP + kk * 32 + lg * 8 + 4];
        qfr[qt][kk] = __builtin_shufflevector(a0, a1, 0, 1, 2, 3, 4, 5, 6, 7);
      }
    v4f accO[2][5];
#pragma unroll
    for (int qt = 0; qt < 2; ++qt)
#pragma unroll
      for (int ft = 0; ft < 5; ++ft) accO[qt][ft] = (v4f){0.f, 0.f, 0.f, 0.f};

    for (int s = 0; s < 8; ++s) {
      if (s == 4) {
        // ---- fused softmax on rows grp, grp+16: one read pass into regs ----
#pragma unroll
        for (int rr = 0; rr < 2; ++rr) {
          const int row = grp + rr * 16;
          _Float16* srow = &s_lds[row * SP];
          v2h ev[16];
          float m = -1e30f;
#pragma unroll
          for (int k = 0; k < 16; ++k) {
            ev[k] = *(const v2h*)&srow[lane * 2 + k * 64];
            m = fmaxf(m, fmaxf((float)ev[k][0], (float)ev[k][1]));
          }
#pragma unroll
          for (int mk = 16; mk; mk >>= 1) m = fmaxf(m, __shfl_xor(m, mk, 32));
          float d = 0.f;
#pragma unroll
          for (int k = 0; k < 16; ++k) {
            float e0 = __expf((float)ev[k][0] - m);
            float e1 = __expf((float)ev[k][1] - m);
            d += e0 + e1;
            v2h w2;
            w2[0] = (_Float16)e0;
            w2[1] = (_Float16)e1;
            ev[k] = w2;
            *(v2h*)&srow[lane * 2 + k * 64] = w2;
          }
#pragma unroll
          for (int mk = 16; mk; mk >>= 1) d += __shfl_xor(d, mk, 32);
          float inv = 1.f / d;
          if (lane == 0) inv_lds[row] = inv;
#pragma unroll
          for (int k = 0; k < 16; ++k) {
            avg[rr][2 * k] += (float)ev[k][0] * inv;
            avg[rr][2 * k + 1] += (float)ev[k][1] * inv;
          }
        }
        __syncthreads();  // P final before cross-row PV reads
      }
      if (s < 4) {
        // ---- QK on kst = K chunk s; swapped operands: A=K, B=Q ----
#pragma unroll
        for (int tt = 0; tt < 2; ++tt) {
          const int rowb = (w * 2 + tt) * 16;
          const int rbase = (rowb + lm) * KP;
          v8h kfr[3];
#pragma unroll
          for (int kk = 0; kk < 3; ++kk) {
            v4h b0 = *(const v4h*)&kst[rbase + kk * 32 + lg * 8];
            v4h b1 = *(const v4h*)&kst[rbase + kk * 32 + lg * 8 + 4];
            kfr[kk] = __builtin_shufflevector(b0, b1, 0, 1, 2, 3, 4, 5, 6, 7);
          }
          const int sc = s * 256 + rowb + lg * 4;
#pragma unroll
          for (int qt = 0; qt < 2; ++qt) {
            v4f acc = (v4f){0.f, 0.f, 0.f, 0.f};
#pragma unroll
            for (int kk = 0; kk < 3; ++kk)
              acc = __builtin_amdgcn_mfma_f32_16x16x32_f16(kfr[kk],
                                                           qfr[qt][kk], acc,
                                                           0, 0, 0);
            v4h o;
#pragma unroll
            for (int r = 0; r < 4; ++r) o[r] = (_Float16)acc[r];
            *(v4h*)&s_lds[(qt * 16 + lm) * SP + sc] = o;
          }
        }
      } else {
        // ---- PV on kst = V^T chunk s-4; contiguous B fragments ----
        const int vcb = (s - 4) * 256;
        v8h pfr[2];
#pragma unroll
        for (int qt = 0; qt < 2; ++qt)
          pfr[qt] =
              *(const v8h*)&s_lds[(qt * 16 + lm) * SP + vcb + w * 32 + lg * 8];
#pragma unroll
        for (int ft = 0; ft < 5; ++ft) {
          v8h bfr = *(const v8h*)&kst[(ft * 16 + lm) * VP + w * 32 + lg * 8];
          accO[0][ft] = __builtin_amdgcn_mfma_f32_16x16x32_f16(
              pfr[0], bfr, accO[0][ft], 0, 0, 0);
          accO[1][ft] = __builtin_amdgcn_mfma_f32_16x16x32_f16(
              pfr[1], bfr, accO[1][ft], 0, 0, 0);
        }
      }
      __syncthreads();  // all consumers of kst chunk s done
      if (s < 7) {
        if (s + 1 < 4) lwriteK(); else lwriteV();  // chunk s+1 -> kst
        int ns = s + 2;
        if (ns < 4) gloadK(kb, ns);
        else if (ns < 8) gloadV(vt4, ns - 4);
        else if (h < 7)
          gloadK(qkv + (size_t)(b * 24 + 8 + h + 1) * NT * FP, 0);
        __syncthreads();  // chunk s+1 visible
      }
    }
    // ---- O epilogue: scale by inv, cross-wave reduce via s_lds (P dead) ----
    float* ored = (float*)s_lds;  // [8][16][84]
#pragma unroll
    for (int qt = 0; qt < 2; ++qt) {
#pragma unroll
      for (int ft = 0; ft < 5; ++ft)
#pragma unroll
        for (int r = 0; r < 4; ++r)
          ored[(w * 16 + lg * 4 + r) * 84 + ft * 16 + lm] =
              accO[qt][ft][r] * inv_lds[qt * 16 + lg * 4 + r];
      __syncthreads();
      for (int i = tid; i < 1280; i += 512) {
        int q = i / 80, f = i % 80;
        float ss = 0.f;
#pragma unroll
        for (int ww = 0; ww < 8; ++ww) ss += ored[(ww * 16 + q) * 84 + f];
        attn_out[((size_t)(b * 16 + h) * NT + t0 + qt * 16 + q) * NF + f] =
            (_Float16)ss;
      }
      __syncthreads();
    }
  }
  // ---- aw head-average write (row-contiguous float2) ----
#pragma unroll
  for (int rr = 0; rr < 2; ++rr) {
    float* ab = aw_avg + ((size_t)b * NT + t0 + grp + rr * 16) * NT;
#pragma unroll
    for (int k = 0; k < 16; ++k) {
      float2 v2;
      v2.x = avg[rr][2 * k] * 0.125f;
      v2.y = avg[rr][2 * k + 1] * 0.125f;
      *(float2*)&ab[lane * 2 + k * 64] = v2;
    }
  }
}

// ---------------------------------------------------------------------------
// Freq attention stage 1 (unchanged)
// ---------------------------------------------------------------------------
__global__ __launch_bounds__(64) void freq_qk_k(
    const _Float16* __restrict__ qkv, float* __restrict__ Cp) {
  __shared__ _Float16 qs[128 * 100];
  __shared__ _Float16 ks[128 * 100];
  const int tc = blockIdx.x, bh = blockIdx.y;
  const int b = bh >> 3, h = bh & 7;
  const int t0 = tc * 128;
  const _Float16* qb = qkv + ((size_t)(b * 24 + h) * NT + t0) * FP;
  const _Float16* kb = qkv + ((size_t)(b * 24 + 8 + h) * NT + t0) * FP;
  const int tid = threadIdx.x;
  for (int i = tid; i < 1536; i += 64) {
    int row = i / 12, c = i % 12;
    int4 vq = ((const int4*)qb)[i];
    int4 vk = ((const int4*)kb)[i];
    int2* dq = (int2*)&qs[row * 100 + c * 8];
    dq[0] = make_int2(vq.x, vq.y);
    dq[1] = make_int2(vq.z, vq.w);
    int2* dk = (int2*)&ks[row * 100 + c * 8];
    dk[0] = make_int2(vk.x, vk.y);
    dk[1] = make_int2(vk.z, vk.w);
  }
  __syncthreads();
  const int lg = tid >> 4, lm = tid & 15;
  v4f acc[5][5];
#pragma unroll
  for (int fr = 0; fr < 5; ++fr)
#pragma unroll
    for (int gc = 0; gc < 5; ++gc) acc[fr][gc] = (v4f){0.f, 0.f, 0.f, 0.f};
#pragma unroll
  for (int kk = 0; kk < 4; ++kk) {
    v8h afr[5];
#pragma unroll
    for (int fr = 0; fr < 5; ++fr)
#pragma unroll
      for (int j = 0; j < 8; ++j)
        afr[fr][j] = qs[(kk * 32 + lg * 8 + j) * 100 + fr * 16 + lm];
#pragma unroll
    for (int gc = 0; gc < 5; ++gc) {
      v8h bfr;
#pragma unroll
      for (int j = 0; j < 8; ++j)
        bfr[j] = ks[(kk * 32 + lg * 8 + j) * 100 + gc * 16 + lm];
#pragma unroll
      for (int fr = 0; fr < 5; ++fr)
        acc[fr][gc] = __builtin_amdgcn_mfma_f32_16x16x32_f16(afr[fr], bfr,
                                                             acc[fr][gc], 0,
                                                             0, 0);
    }
  }
  float* cpb = Cp + ((size_t)bh * 8 + tc) * 6400;
#pragma unroll
  for (int fr = 0; fr < 5; ++fr)
#pragma unroll
    for (int gc = 0; gc < 5; ++gc)
#pragma unroll
      for (int r = 0; r < 4; ++r)
        cpb[(fr * 16 + lg * 4 + r) * 80 + gc * 16 + lm] = acc[fr][gc][r];
}

// ---------------------------------------------------------------------------
// Freq attention stage 2: cooperative coalesced partial-sum into LDS, then
// row softmax from LDS. Grid 128 (bh), 256 threads.
// ---------------------------------------------------------------------------
__global__ __launch_bounds__(256) void freq_sm_k(const float* __restrict__ Cp,
                                                 _Float16* __restrict__ P) {
  __shared__ float cs[6400];  // [80][80], 25.6 KB
  const int bh = blockIdx.x;
  const int tid = threadIdx.x;
  const float4* base = (const float4*)(Cp + (size_t)bh * 8 * 6400);
  for (int i = tid; i < 1600; i += 256) {
    float4 a = base[i];
#pragma unroll
    for (int tc = 1; tc < 8; ++tc) {
      float4 v = base[tc * 1600 + i];
      a.x += v.x;
      a.y += v.y;
      a.z += v.z;
      a.w += v.w;
    }
    ((float4*)cs)[i] = a;
  }
  __syncthreads();
  const int f = tid;
  if (f >= 80) return;
  const float* row = &cs[f * 80];
  float m = -1e30f;
#pragma unroll
  for (int g = 0; g < 80; ++g) m = fmaxf(m, row[g]);
  float d = 0.f;
  float e[80];
#pragma unroll
  for (int g = 0; g < 80; ++g) {
    e[g] = __expf(row[g] - m);
    d += e[g];
  }
  float inv = 1.f / d;
  _Float16* pb = P + (size_t)bh * 80 * 96 + (size_t)f * 96;
#pragma unroll
  for (int c8 = 0; c8 < 10; ++c8) {
    v8h v;
#pragma unroll
    for (int j = 0; j < 8; ++j) v[j] = (_Float16)(e[c8 * 8 + j] * inv);
    *(v8h*)(pb + c8 * 8) = v;
  }
  v8h z = (v8h)(_Float16)0.f;
  *(v8h*)(pb + 80) = z;
  *(v8h*)(pb + 88) = z;
}

// ---------------------------------------------------------------------------
// Freq attention stage 3 (attn output now fp16)
// ---------------------------------------------------------------------------
__global__ __launch_bounds__(256) void freq_pv_k(
    const _Float16* __restrict__ qkv, const _Float16* __restrict__ P,
    _Float16* __restrict__ attn_out) {
  __shared__ _Float16 vs[128 * 104];
  __shared__ _Float16 ps[80 * 104];
  const int tc = blockIdx.x, bh = blockIdx.y;
  const int b = bh >> 3, h = bh & 7;
  const int t0 = tc * 128;
  const _Float16* vb = qkv + ((size_t)(b * 24 + 16 + h) * NT + t0) * FP;
  const _Float16* pb = P + (size_t)bh * 80 * 96;
  const int tid = threadIdx.x;
  for (int i = tid; i < 1536; i += 256) {
    int row = i / 12, c = i % 12;
    *(int4*)&vs[row * 104 + c * 8] = ((const int4*)vb)[i];
  }
  for (int i = tid; i < 960; i += 256) {
    int row = i / 12, c = i % 12;
    *(int4*)&ps[row * 104 + c * 8] = ((const int4*)pb)[i];
  }
  __syncthreads();
  const int w = tid >> 6, l = tid & 63, lg = l >> 4, lm = l & 15;
  v8h bfr[5][3];
#pragma unroll
  for (int fc = 0; fc < 5; ++fc)
#pragma unroll
    for (int kk = 0; kk < 3; ++kk)
      bfr[fc][kk] = *(const v8h*)&ps[(fc * 16 + lm) * 104 + kk * 32 + lg * 8];
#pragma unroll
  for (int tt2 = 0; tt2 < 2; ++tt2) {
    const int tt = w + tt2 * 4;
    v8h afr[3];
#pragma unroll
    for (int kk = 0; kk < 3; ++kk)
      afr[kk] = *(const v8h*)&vs[(tt * 16 + lm) * 104 + kk * 32 + lg * 8];
    _Float16* ob =
        attn_out + ((size_t)(b * 16 + 8 + h) * NT + t0 + tt * 16) * NF;
#pragma unroll
    for (int fc = 0; fc < 5; ++fc) {
      v4f acc = (v4f){0.f, 0.f, 0.f, 0.f};
#pragma unroll
      for (int kk = 0; kk < 3; ++kk)
        acc = __builtin_amdgcn_mfma_f32_16x16x32_f16(afr[kk], bfr[fc][kk],
                                                     acc, 0, 0, 0);
#pragma unroll
      for (int r = 0; r < 4; ++r)
        ob[(lg * 4 + r) * NF + fc * 16 + lm] = (_Float16)acc[r];
    }
  }
}

// BN + relu: read fp16 y, write final fp32 out
__global__ __launch_bounds__(256) void bn_apply_out_k(
    const _Float16* __restrict__ y, const float* __restrict__ stats,
    const float* __restrict__ go, const float* __restrict__ bo,
    float* __restrict__ out) {
  const size_t n8 = OUT_ELEMS / 8;
  const size_t stride = (size_t)gridDim.x * blockDim.x;
  for (size_t idx = (size_t)blockIdx.x * blockDim.x + threadIdx.x; idx < n8;
       idx += stride) {
    int c = (int)((idx / (NT * NF / 8)) % 16);
    float g = go[c], be = bo[c];
    float mean = stats[c * 2 + 0], invstd = stats[c * 2 + 1];
    v8h v = ((const v8h*)y)[idx];
    float4 o0, o1;
    o0.x = fmaxf(((float)v[0] - mean) * invstd * g + be, 0.f);
    o0.y = fmaxf(((float)v[1] - mean) * invstd * g + be, 0.f);
    o0.z = fmaxf(((float)v[2] - mean) * invstd * g + be, 0.f);
    o0.w = fmaxf(((float)v[3] - mean) * invstd * g + be, 0.f);
    o1.x = fmaxf(((float)v[4] - mean) * invstd * g + be, 0.f);
    o1.y = fmaxf(((float)v[5] - mean) * invstd * g + be, 0.f);
    o1.z = fmaxf(((float)v[6] - mean) * invstd * g + be, 0.f);
    o1.w = fmaxf(((float)v[7] - mean) * invstd * g + be, 0.f);
    ((float4*)out)[idx * 2] = o0;
    ((float4*)out)[idx * 2 + 1] = o1;
  }
}

// ---------------------------------------------------------------------------
extern "C" void kernel_launch(void* const* d_in, const int* in_sizes, int n_in,
                              void* d_out, int out_size, void* d_ws,
                              size_t ws_size, hipStream_t stream) {
  const float* x = (const float*)d_in[0];
  const float* w_in = (const float*)d_in[1];
  const float* b_in = (const float*)d_in[2];
  const float* w_out = (const float*)d_in[3];
  const float* b_out = (const float*)d_in[4];
  const float* gq = (const float*)d_in[5];
  const float* bq = (const float*)d_in[6];
  const float* gk = (const float*)d_in[7];
  const float* bk = (const float*)d_in[8];
  const float* gv = (const float*)d_in[9];
  const float* bv = (const float*)d_in[10];
  const float* go = (const float*)d_in[11];
  const float* bo = (const float*)d_in[12];

  float* out = (float*)d_out;                    // (16,16,1024,80) fp32
  float* aw = out + OUT_ELEMS;                   // (16,1024,1024) fp32
  _Float16* attnh = (_Float16*)d_out;            // fp16 attn staged in dead
                                                 // out region [0, 42 MB)
  char* wsb = (char*)d_ws;
  _Float16* qkvb = (_Float16*)wsb;               // [0, 75.5 MB)
  _Float16* yh = (_Float16*)wsb;                 // fp16 y aliases dead qkvb
  _Float16* vTb = (_Float16*)(wsb + 75497472);   // 21 MB vT (dead before Cp)
  float* Cp = (float*)(wsb + 75497472);          // 26.2 MB freq partials
  _Float16* Pf = (_Float16*)(wsb + 101711872);   // 1.97 MB freq probs
  float* pstats = (float*)(wsb + 119537664);     // 2*24*1024 floats (196 KB)
  float* stats1 = pstats + 49152;
  float* stats2 = stats1 + 48;

  // conv_in (fused channels-last staging from fp32 NCHW) + BN partials
  conv_mfma_k<float, 2, FP, true, true>
      <<<dim3(64, 16), 512, 0, stream>>>(x, w_in, b_in, qkvb, pstats, 24);
  bn_finalize2_k<<<24, 256, 0, stream>>>(pstats, stats1, 24);
  bn_apply_qk_k<<<2048, 256, 0, stream>>>(qkvb, stats1, gq, bq, gk, bk);
  vtrans_bn_k<<<dim3(8, 128), 256, 0, stream>>>(qkvb, stats1, gv, bv, vTb);
  time_attn_k<<<dim3(32, 16), 512, 0, stream>>>(qkvb, vTb, attnh, aw);
  freq_qk_k<<<dim3(8, 128), 64, 0, stream>>>(qkvb, Cp);
  freq_sm_k<<<128, 256, 0, stream>>>(Cp, Pf);
  freq_pv_k<<<dim3(8, 128), 256, 0, stream>>>(qkvb, Pf, attnh);
  // conv_out (fused channels-last staging from fp16 attn) + BN partials
  conv_mfma_k<_Float16, 1, NF, false, false>
      <<<dim3(64, 16), 512, 0, stream>>>(attnh, w_out, b_out, yh, pstats, 16);
  bn_finalize2_k<<<16, 256, 0, stream>>>(pstats, stats2, 16);
  bn_apply_out_k<<<2048, 256, 0, stream>>>(yh, stats2, go, bo, out);
}